// Round 3
// baseline (3024.624 us; speedup 1.0000x reference)
//
#include <hip/hip_runtime.h>
#include <math.h>

#define N_NODES 25000
#define N_EDGES 400000
#define HID 128
#define EDGE_F 16
#define ADY 64
#define INNER 160
#define MSG_F 273   // 2*HID + 1 + EDGE_F
#define HEADS 8
#define TE 32       // edges per tile in edge kernel

// element offsets inside d_out (h2 | coords | res2), dtype-independent
#define OUT_CRD (N_NODES * HID)          // 3,200,000
#define OUT_RES (N_NODES * (HID + 3))    // 3,275,000

// ws byte offsets (all 16-aligned)
#define FLAG_OFF 0
#define DEN_OFF  256
#define CACC_OFF 800256
#define HAGG_OFF 1100288
#define TWS_OFF  HAGG_OFF            // aliases hagg (dead after node1)
#define CW_BASE  13900288            // canonical bf16 weights start
#define MEMSET_BYTES 13900288

typedef unsigned short u16;
typedef unsigned int u32;
typedef unsigned long long u64;

__device__ __forceinline__ float bf2f(u16 v) {
    union { u32 u; float f; } x; x.u = ((u32)v) << 16; return x.f;
}
__device__ __forceinline__ u16 f2bf(float f) {
    union { float ff; u32 u; } x; x.ff = f;
    u32 u = x.u;
    u32 rounding = 0x7FFFu + ((u >> 16) & 1u);
    u += rounding;
    return (u16)(u >> 16);
}
__device__ __forceinline__ void bf2x2(u32 p, float& lo, float& hi) {
    union { u32 u; float f; } a, b;
    a.u = p << 16; b.u = p & 0xFFFF0000u;
    lo = a.f; hi = b.f;
}
__device__ __forceinline__ float silu(float z) {
    z = fminf(fmaxf(z, -30000.f), 30000.f);
    return z / (1.0f + __expf(-z));
}

// dtype-generic scalar load/store (element index; F32 decides element size)
template<bool F32> __device__ __forceinline__ float ldg1(const void* p, size_t i) {
    if (F32) return ((const float*)p)[i];
    return bf2f(((const u16*)p)[i]);
}
template<bool F32> __device__ __forceinline__ void stg1(void* p, size_t i, float v) {
    if (F32) ((float*)p)[i] = v;
    else     ((u16*)p)[i] = f2bf(v);
}
// 8 contiguous elements -> bf16, dst 16B-aligned
template<bool F32> __device__ __forceinline__ void ld8a(const void* p, size_t i, u16* dst) {
    if (F32) {
        const float* fp = (const float*)p + i;
        float4 v0 = ((const float4*)fp)[0];
        float4 v1 = ((const float4*)fp)[1];
        u16 tmp[8] = { f2bf(v0.x), f2bf(v0.y), f2bf(v0.z), f2bf(v0.w),
                       f2bf(v1.x), f2bf(v1.y), f2bf(v1.z), f2bf(v1.w) };
        *(uint4*)dst = *(const uint4*)tmp;
    } else {
        *(uint4*)dst = *(const uint4*)((const u16*)p + i);
    }
}
// 8 contiguous elements -> bf16, dst unaligned (scalar stores)
template<bool F32> __device__ __forceinline__ void ld8u(const void* p, size_t i, u16* dst) {
    if (F32) {
        const float* fp = (const float*)p + i;
        float4 v0 = ((const float4*)fp)[0];
        float4 v1 = ((const float4*)fp)[1];
        dst[0]=f2bf(v0.x); dst[1]=f2bf(v0.y); dst[2]=f2bf(v0.z); dst[3]=f2bf(v0.w);
        dst[4]=f2bf(v1.x); dst[5]=f2bf(v1.y); dst[6]=f2bf(v1.z); dst[7]=f2bf(v1.w);
    } else {
        uint4 v = *(const uint4*)((const u16*)p + i);
        u32 arr[4] = {v.x, v.y, v.z, v.w};
        #pragma unroll
        for (int q = 0; q < 4; q++) {
            dst[2*q+0] = (u16)(arr[q] & 0xFFFFu);
            dst[2*q+1] = (u16)(arr[q] >> 16);
        }
    }
}

// ---------------------------------------------------------------------------
// dtype detector: sample even u16s of h. True bf16 data -> genuine small
// values. fp32 data -> low mantissa halves: huge bf2f magnitudes (or all
// zero if the fp32 came from a bf16 upcast). flag=1 means fp32.
// ---------------------------------------------------------------------------
__global__ void detect_kernel(const void* h, int* flag) {
    __shared__ float red[256];
    const int t = threadIdx.x;
    const u16* p = (const u16*)h;
    float mx = 0.f;
    for (int i = 0; i < 64; i++) {
        int idx = (t * 64 + i) * 97;          // < 1,589,152
        float v = fabsf(bf2f(p[idx * 2]));    // even index, < 3.2M u16s (safe both dtypes)
        mx = fmaxf(mx, v);                    // fmaxf ignores NaN
    }
    red[t] = mx;
    __syncthreads();
    for (int s = 128; s > 0; s >>= 1) {
        if (t < s) red[t] = fmaxf(red[t], red[t + s]);
        __syncthreads();
    }
    if (t == 0) flag[0] = (red[0] > 1e10f || red[0] == 0.f) ? 1 : 0;
}

// ---------------------------------------------------------------------------
// weight canonicalization: 16 tensors -> bf16 copies in ws
// ---------------------------------------------------------------------------
struct CvtArgs {
    const void* src[16];
    u64 dstoff[16];
    int n[16];
};
__global__ void cvt_kernel(const int* __restrict__ flag, char* wsbase, CvtArgs args) {
    const int ten = blockIdx.y;
    const void* s = args.src[ten];
    u16* d = (u16*)(wsbase + args.dstoff[ten]);
    const int n = args.n[ten];
    const bool f32 = (*flag != 0);
    if (f32) {
        const float* sf = (const float*)s;
        for (int i = blockIdx.x * 256 + threadIdx.x; i < n; i += gridDim.x * 256)
            d[i] = f2bf(sf[i]);
    } else {
        const u16* su = (const u16*)s;
        for (int i = blockIdx.x * 256 + threadIdx.x; i < n; i += gridDim.x * 256)
            d[i] = su[i];
    }
}

// ---------------------------------------------------------------------------
// Fused edge kernel body (templated on input dtype).
// f = [h[src], h[dst], r2, a] -> m1 = silu(f@We1+be1) -> m2 = silu(m1@We2+be2)
// -> heads: den[dst] += exp(Wa), cacc[dst] += Wc*diff*inv, hagg[dst] += exp*Wv
// ---------------------------------------------------------------------------
template<bool F32>
__device__ __forceinline__ void edge_body(
    const void* h, const void* coords, const void* a,
    const int* __restrict__ src, const int* __restrict__ dst,
    const u16* __restrict__ We1, const u16* __restrict__ be1,
    const u16* __restrict__ We2, const u16* __restrict__ be2,
    const u16* __restrict__ Wc,  const u16* __restrict__ Wv,
    const u16* __restrict__ Wa,
    float* __restrict__ den, float* __restrict__ hagg, float* __restrict__ cacc,
    u16* sw, u16* sfc, float* sm, float* sWa, float* sWc,
    float* sbe1, float* sbe2, float* sex, float* sdiff, float* srad,
    int* ssrc, int* sdstl)
{
    const int t  = threadIdx.x;
    const int tx = t & 15;
    const int ty = t >> 4;

    for (int i = t; i < INNER * 8; i += 256) sWa[i] = bf2f(Wa[i]);
    for (int i = t; i < INNER; i += 256) {
        sWc[i]  = bf2f(Wc[i]);
        sbe1[i] = bf2f(be1[i]);
        sbe2[i] = bf2f(be2[i]);
    }

    for (int tile = blockIdx.x; tile < N_EDGES / TE; tile += gridDim.x) {
        const int e0 = tile * TE;
        __syncthreads();   // prev tile fully done
        if (t < TE) {
            int e = e0 + t;
            int s = src[e], d = dst[e];
            ssrc[t] = s; sdstl[t] = d;
            float dx = ldg1<F32>(coords, (size_t)s*3+0) - ldg1<F32>(coords, (size_t)d*3+0);
            float dy = ldg1<F32>(coords, (size_t)s*3+1) - ldg1<F32>(coords, (size_t)d*3+1);
            float dz = ldg1<F32>(coords, (size_t)s*3+2) - ldg1<F32>(coords, (size_t)d*3+2);
            sdiff[t*4+0] = dx; sdiff[t*4+1] = dy; sdiff[t*4+2] = dz;
            float r2 = dx*dx + dy*dy + dz*dz;
            srad[t] = r2;
            sdiff[t*4+3] = 1.0f / (sqrtf(r2 + 1e-5f) + 1.0f);
        }
        __syncthreads();

        // ---- Layer 1: z1 = f @ We1 + be1, K=273 in 5 chunks ----
        float acc[2][10];
        #pragma unroll
        for (int p = 0; p < 2; p++)
            #pragma unroll
            for (int j = 0; j < 10; j++) acc[p][j] = sbe1[tx*10 + j];

        for (int c = 0; c < 5; c++) {
            const int kbase = c * 64;
            const int rows  = (c < 4) ? 64 : (MSG_F - 256);   // 17
            __syncthreads();
            {   // stage We1 rows
                int nvec = (rows * INNER * 2) >> 4;
                const uint4* g4 = (const uint4*)(We1 + kbase * INNER);
                uint4* s4 = (uint4*)sw;
                for (int i = t; i < nvec; i += 256) s4[i] = g4[i];
            }
            if (c < 4) {       // gather h rows
                int e = t >> 3, part = t & 7;
                int node = (c < 2) ? ssrc[e] : sdstl[e];
                int koff = (c & 1) * 64 + part * 8;
                ld8a<F32>(h, (size_t)node * HID + koff, &sfc[e*72 + part*8]);
            } else {           // rows 257..272: a[0:16]  (row 256 = srad)
                if (t >= 32 && t < 96) {
                    int e = (t - 32) >> 1, half = (t - 32) & 1;
                    ld8u<F32>(a, (size_t)(e0 + e) * EDGE_F + half * 8,
                              &sfc[e*72 + 1 + half*8]);
                }
            }
            __syncthreads();
            for (int k = 0; k < rows; k++) {
                float w[10];
                const u32* wrow = (const u32*)(&sw[k*INNER + tx*10]);
                #pragma unroll
                for (int q = 0; q < 5; q++) bf2x2(wrow[q], w[2*q], w[2*q+1]);
                #pragma unroll
                for (int p = 0; p < 2; p++) {
                    int edge = ty*2 + p;
                    float fv = (c == 4 && k == 0) ? srad[edge]
                                                  : bf2f(sfc[edge*72 + k]);
                    #pragma unroll
                    for (int j = 0; j < 10; j++) acc[p][j] += fv * w[j];
                }
            }
        }
        #pragma unroll
        for (int p = 0; p < 2; p++)
            #pragma unroll
            for (int j = 0; j < 10; j++)
                sm[(ty*2+p)*161 + tx*10 + j] = silu(acc[p][j]);

        // ---- Layer 2: z2 = m1 @ We2 + be2, K=160 ----
        float acc2[2][10];
        #pragma unroll
        for (int p = 0; p < 2; p++)
            #pragma unroll
            for (int j = 0; j < 10; j++) acc2[p][j] = sbe2[tx*10 + j];

        for (int c = 0; c < 3; c++) {
            const int kbase = c * 64;
            const int rows  = (c < 2) ? 64 : 32;
            __syncthreads();
            {
                int nvec = (rows * INNER * 2) >> 4;
                const uint4* g4 = (const uint4*)(We2 + kbase * INNER);
                uint4* s4 = (uint4*)sw;
                for (int i = t; i < nvec; i += 256) s4[i] = g4[i];
            }
            __syncthreads();
            for (int k = 0; k < rows; k++) {
                float w[10];
                const u32* wrow = (const u32*)(&sw[k*INNER + tx*10]);
                #pragma unroll
                for (int q = 0; q < 5; q++) bf2x2(wrow[q], w[2*q], w[2*q+1]);
                #pragma unroll
                for (int p = 0; p < 2; p++) {
                    float mv = sm[(ty*2+p)*161 + kbase + k];
                    #pragma unroll
                    for (int j = 0; j < 10; j++) acc2[p][j] += mv * w[j];
                }
            }
        }
        float m2r[2][10];
        #pragma unroll
        for (int p = 0; p < 2; p++)
            #pragma unroll
            for (int j = 0; j < 10; j++) m2r[p][j] = silu(acc2[p][j]);
        __syncthreads();                 // all m1 reads done
        #pragma unroll
        for (int p = 0; p < 2; p++)
            #pragma unroll
            for (int j = 0; j < 10; j++)
                sm[(ty*2+p)*161 + tx*10 + j] = m2r[p][j];
        __syncthreads();                 // m2 visible

        // ---- phase C (t<32, one edge each): Wa/Wc heads ----
        if (t < TE) {
            int e = t;
            float la[8] = {0,0,0,0,0,0,0,0};
            float lc = 0.f;
            for (int k = 0; k < INNER; k++) {
                float mk = sm[e*161 + k];
                #pragma unroll
                for (int o = 0; o < 8; o++) la[o] += mk * sWa[k*8 + o];
                lc += mk * sWc[k];
            }
            int d = sdstl[e];
            #pragma unroll
            for (int o = 0; o < 8; o++) {
                float ex = __expf(fminf(fmaxf(la[o], -30.f), 30.f));
                sex[e*8 + o] = ex;
                atomicAdd(&den[(size_t)d*8 + o], ex);
            }
            float invf = sdiff[e*4 + 3];
            lc = fminf(fmaxf(lc, -1e6f), 1e6f);
            #pragma unroll
            for (int j = 0; j < 3; j++)
                atomicAdd(&cacc[(size_t)d*3 + j], lc * sdiff[e*4 + j] * invf);
        }

        // ---- phase B: v = m2 @ Wv, K=160 ----
        float av[2][8];
        #pragma unroll
        for (int p = 0; p < 2; p++)
            #pragma unroll
            for (int j = 0; j < 8; j++) av[p][j] = 0.f;
        for (int c = 0; c < 3; c++) {
            const int kbase = c * 64;
            const int rows  = (c < 2) ? 64 : 32;
            __syncthreads();
            {
                int nvec = (rows * HID * 2) >> 4;
                const uint4* g4 = (const uint4*)(Wv + kbase * HID);
                uint4* s4 = (uint4*)sw;
                for (int i = t; i < nvec; i += 256) s4[i] = g4[i];
            }
            __syncthreads();
            for (int k = 0; k < rows; k++) {
                float w[8];
                const u32* wrow = (const u32*)(&sw[k*HID + tx*8]);
                #pragma unroll
                for (int q = 0; q < 4; q++) bf2x2(wrow[q], w[2*q], w[2*q+1]);
                #pragma unroll
                for (int p = 0; p < 2; p++) {
                    float mv = sm[(ty*2+p)*161 + kbase + k];
                    #pragma unroll
                    for (int j = 0; j < 8; j++) av[p][j] += mv * w[j];
                }
            }
        }
        // ---- phase D: weighted scatter into hagg ----
        #pragma unroll
        for (int p = 0; p < 2; p++) {
            int e = ty*2 + p;
            int d = sdstl[e];
            float exh = sex[e*8 + (tx >> 1)];
            #pragma unroll
            for (int j = 0; j < 8; j++)
                atomicAdd(&hagg[(size_t)d*HID + tx*8 + j], av[p][j] * exh);
        }
    }
}

__global__ __launch_bounds__(256, 1)
void edge_kernel(const int* __restrict__ flag,
                 const void* h, const void* coords, const void* a,
                 const int* __restrict__ src, const int* __restrict__ dst,
                 const u16* __restrict__ We1, const u16* __restrict__ be1,
                 const u16* __restrict__ We2, const u16* __restrict__ be2,
                 const u16* __restrict__ Wc,  const u16* __restrict__ Wv,
                 const u16* __restrict__ Wa,
                 float* __restrict__ den, float* __restrict__ hagg,
                 float* __restrict__ cacc)
{
    __shared__ __align__(16) u16   sw[64 * INNER];
    __shared__ __align__(16) u16   sfc[TE * 72];
    __shared__ float sm[TE * 161];
    __shared__ float sWa[INNER * 8];
    __shared__ float sWc[INNER];
    __shared__ float sbe1[INNER];
    __shared__ float sbe2[INNER];
    __shared__ float sex[TE * 8];
    __shared__ float sdiff[TE * 4];
    __shared__ float srad[TE];
    __shared__ int   ssrc[TE];
    __shared__ int   sdstl[TE];
    if (*flag)
        edge_body<true>(h, coords, a, src, dst, We1, be1, We2, be2, Wc, Wv, Wa,
                        den, hagg, cacc, sw, sfc, sm, sWa, sWc, sbe1, sbe2,
                        sex, sdiff, srad, ssrc, sdstl);
    else
        edge_body<false>(h, coords, a, src, dst, We1, be1, We2, be2, Wc, Wv, Wa,
                         den, hagg, cacc, sw, sfc, sm, sWa, sWc, sbe1, sbe2,
                         sex, sdiff, srad, ssrc, sdstl);
}

// ---------------------------------------------------------------------------
// node1: h_agg = hagg/den; f2 = h_agg@Wo; res1 = res+f2 -> out_res slot;
// h1 = adaLN(h+f2, FiLM1(y)) -> out_h2 slot; coords_out = coords + cacc.
// ---------------------------------------------------------------------------
template<bool F32>
__device__ __forceinline__ void node1_body(
    const void* h, const void* res, const void* coords, const void* y,
    const u16* __restrict__ Wo, const u16* __restrict__ Wf1,
    const u16* __restrict__ bf1v,
    const float* __restrict__ den, const float* __restrict__ hagg,
    const float* __restrict__ cacc, void* out, u16* sWo, u16* sWf)
{
    const int t = threadIdx.x, wid = t >> 6, lane = t & 63;
    const int c0 = lane, c1 = lane + 64;
    for (int i = t; i < (HID*HID)/8; i += 256) ((uint4*)sWo)[i] = ((const uint4*)Wo)[i];
    for (int i = t; i < (ADY*256)/8; i += 256) ((uint4*)sWf)[i] = ((const uint4*)Wf1)[i];
    float b_sc0 = bf2f(bf1v[c0]),       b_sc1 = bf2f(bf1v[c1]);
    float b_sh0 = bf2f(bf1v[128 + c0]), b_sh1 = bf2f(bf1v[128 + c1]);
    __syncthreads();
    for (int n = blockIdx.x*4 + wid; n < N_NODES; n += 2500) {
        float dd0 = den[(size_t)n*8 + (c0 >> 4)];
        float dd1 = den[(size_t)n*8 + (c1 >> 4)];
        float g0 = dd0 > 0.f ? hagg[(size_t)n*HID + c0] / dd0 : 0.f;
        float g1 = dd1 > 0.f ? hagg[(size_t)n*HID + c1] / dd1 : 0.f;
        float f20 = 0.f, f21 = 0.f;
        for (int k = 0; k < 64; k++) {
            float hk = __shfl(g0, k);
            f20 += hk * bf2f(sWo[k*HID + c0]);
            f21 += hk * bf2f(sWo[k*HID + c1]);
        }
        for (int k = 0; k < 64; k++) {
            float hk = __shfl(g1, k);
            f20 += hk * bf2f(sWo[(k+64)*HID + c0]);
            f21 += hk * bf2f(sWo[(k+64)*HID + c1]);
        }
        stg1<F32>(out, (size_t)OUT_RES + (size_t)n*HID + c0,
                  ldg1<F32>(res, (size_t)n*HID + c0) + f20);
        stg1<F32>(out, (size_t)OUT_RES + (size_t)n*HID + c1,
                  ldg1<F32>(res, (size_t)n*HID + c1) + f21);
        float x0 = ldg1<F32>(h, (size_t)n*HID + c0) + f20;
        float x1 = ldg1<F32>(h, (size_t)n*HID + c1) + f21;
        float s = x0 + x1, q = x0*x0 + x1*x1;
        for (int off = 32; off > 0; off >>= 1) { s += __shfl_xor(s, off); q += __shfl_xor(q, off); }
        float mu   = s * (1.f/128.f);
        float var  = q * (1.f/128.f) - mu*mu;
        float rstd = rsqrtf(fmaxf(var, 0.f) + 1e-5f);
        float yv = ldg1<F32>(y, (size_t)n*ADY + lane);
        float f_sc0 = b_sc0, f_sc1 = b_sc1, f_sh0 = b_sh0, f_sh1 = b_sh1;
        for (int k = 0; k < 64; k++) {
            float yk = __shfl(yv, k);
            f_sc0 += yk * bf2f(sWf[k*256 + c0]);
            f_sc1 += yk * bf2f(sWf[k*256 + c1]);
            f_sh0 += yk * bf2f(sWf[k*256 + 128 + c0]);
            f_sh1 += yk * bf2f(sWf[k*256 + 128 + c1]);
        }
        stg1<F32>(out, (size_t)n*HID + c0, (x0 - mu)*rstd*(1.f + f_sc0) + f_sh0);
        stg1<F32>(out, (size_t)n*HID + c1, (x1 - mu)*rstd*(1.f + f_sc1) + f_sh1);
        if (lane < 3)
            stg1<F32>(out, (size_t)OUT_CRD + (size_t)n*3 + lane,
                      ldg1<F32>(coords, (size_t)n*3 + lane) + cacc[(size_t)n*3 + lane]);
    }
}

__global__ __launch_bounds__(256, 1)
void node1_kernel(const int* __restrict__ flag,
                  const void* h, const void* res, const void* coords, const void* y,
                  const u16* __restrict__ Wo, const u16* __restrict__ Wf1,
                  const u16* __restrict__ bf1v,
                  const float* __restrict__ den, const float* __restrict__ hagg,
                  const float* __restrict__ cacc, void* out)
{
    __shared__ __align__(16) u16 sWo[HID * HID];
    __shared__ __align__(16) u16 sWf[ADY * 256];
    if (*flag) node1_body<true>(h, res, coords, y, Wo, Wf1, bf1v, den, hagg, cacc, out, sWo, sWf);
    else       node1_body<false>(h, res, coords, y, Wo, Wf1, bf1v, den, hagg, cacc, out, sWo, sWf);
}

// ---------------------------------------------------------------------------
// node2a: t = silu(h1 @ Wn1 + bn1) -> tws (bf16, ws)
// ---------------------------------------------------------------------------
template<bool F32>
__device__ __forceinline__ void node2a_body(
    const void* out, const u16* __restrict__ Wn1, const u16* __restrict__ bn1,
    u16* __restrict__ tws, u16* sW, float* sb)
{
    const int t = threadIdx.x, wid = t >> 6, lane = t & 63;
    for (int i = t; i < (HID*INNER)/8; i += 256) ((uint4*)sW)[i] = ((const uint4*)Wn1)[i];
    for (int i = t; i < INNER; i += 256) sb[i] = bf2f(bn1[i]);
    __syncthreads();
    for (int n = blockIdx.x*4 + wid; n < N_NODES; n += 2500) {
        float a0 = ldg1<F32>(out, (size_t)n*HID + lane);
        float a1 = ldg1<F32>(out, (size_t)n*HID + 64 + lane);
        const int c0 = lane, c1 = lane + 64, c2 = lane + 128;
        float t0 = sb[c0], t1 = sb[c1], t2 = (lane < 32) ? sb[c2] : 0.f;
        for (int k = 0; k < 64; k++) {
            float hk = __shfl(a0, k);
            t0 += hk * bf2f(sW[k*INNER + c0]);
            t1 += hk * bf2f(sW[k*INNER + c1]);
            if (lane < 32) t2 += hk * bf2f(sW[k*INNER + c2]);
        }
        for (int k = 0; k < 64; k++) {
            float hk = __shfl(a1, k);
            t0 += hk * bf2f(sW[(k+64)*INNER + c0]);
            t1 += hk * bf2f(sW[(k+64)*INNER + c1]);
            if (lane < 32) t2 += hk * bf2f(sW[(k+64)*INNER + c2]);
        }
        tws[(size_t)n*INNER + c0] = f2bf(silu(t0));
        tws[(size_t)n*INNER + c1] = f2bf(silu(t1));
        if (lane < 32) tws[(size_t)n*INNER + c2] = f2bf(silu(t2));
    }
}

__global__ __launch_bounds__(256, 1)
void node2a_kernel(const int* __restrict__ flag, const void* out,
                   const u16* __restrict__ Wn1, const u16* __restrict__ bn1,
                   u16* __restrict__ tws)
{
    __shared__ __align__(16) u16 sW[HID * INNER];
    __shared__ float sb[INNER];
    if (*flag) node2a_body<true>(out, Wn1, bn1, tws, sW, sb);
    else       node2a_body<false>(out, Wn1, bn1, tws, sW, sb);
}

// ---------------------------------------------------------------------------
// node2b: f3 = t @ Wn2 + bn2; res2 = res1 + f3 (out res slot, rmw);
// x2 = h1 + f3 overwrites h1 (out h2 slot, rmw).
// ---------------------------------------------------------------------------
template<bool F32>
__device__ __forceinline__ void node2b_body(
    void* out, const u16* __restrict__ tws,
    const u16* __restrict__ Wn2, const u16* __restrict__ bn2,
    u16* sW, float* sb)
{
    const int t = threadIdx.x, wid = t >> 6, lane = t & 63;
    for (int i = t; i < (INNER*HID)/8; i += 256) ((uint4*)sW)[i] = ((const uint4*)Wn2)[i];
    for (int i = t; i < HID; i += 256) sb[i] = bf2f(bn2[i]);
    __syncthreads();
    for (int n = blockIdx.x*4 + wid; n < N_NODES; n += 2500) {
        float b0 = bf2f(tws[(size_t)n*INNER + lane]);
        float b1 = bf2f(tws[(size_t)n*INNER + 64 + lane]);
        float b2 = (lane < 32) ? bf2f(tws[(size_t)n*INNER + 128 + lane]) : 0.f;
        const int c0 = lane, c1 = lane + 64;
        float f0 = sb[c0], f1 = sb[c1];
        for (int k = 0; k < 64; k++) { float tk = __shfl(b0, k); f0 += tk*bf2f(sW[k*HID + c0]);       f1 += tk*bf2f(sW[k*HID + c1]); }
        for (int k = 0; k < 64; k++) { float tk = __shfl(b1, k); f0 += tk*bf2f(sW[(k+64)*HID + c0]);  f1 += tk*bf2f(sW[(k+64)*HID + c1]); }
        for (int k = 0; k < 32; k++) { float tk = __shfl(b2, k); f0 += tk*bf2f(sW[(k+128)*HID + c0]); f1 += tk*bf2f(sW[(k+128)*HID + c1]); }
        stg1<F32>(out, (size_t)OUT_RES + (size_t)n*HID + c0,
                  ldg1<F32>(out, (size_t)OUT_RES + (size_t)n*HID + c0) + f0);
        stg1<F32>(out, (size_t)OUT_RES + (size_t)n*HID + c1,
                  ldg1<F32>(out, (size_t)OUT_RES + (size_t)n*HID + c1) + f1);
        stg1<F32>(out, (size_t)n*HID + c0, ldg1<F32>(out, (size_t)n*HID + c0) + f0);
        stg1<F32>(out, (size_t)n*HID + c1, ldg1<F32>(out, (size_t)n*HID + c1) + f1);
    }
}

__global__ __launch_bounds__(256, 1)
void node2b_kernel(const int* __restrict__ flag, void* out,
                   const u16* __restrict__ tws,
                   const u16* __restrict__ Wn2, const u16* __restrict__ bn2)
{
    __shared__ __align__(16) u16 sW[INNER * HID];
    __shared__ float sb[HID];
    if (*flag) node2b_body<true>(out, tws, Wn2, bn2, sW, sb);
    else       node2b_body<false>(out, tws, Wn2, bn2, sW, sb);
}

// ---------------------------------------------------------------------------
// node3: h2 = adaLN(x2, FiLM2(y)) in place over out h2 slot.
// ---------------------------------------------------------------------------
template<bool F32>
__device__ __forceinline__ void node3_body(
    const void* y, const u16* __restrict__ Wf2, const u16* __restrict__ bf2v,
    void* out, u16* sWf)
{
    const int t = threadIdx.x, wid = t >> 6, lane = t & 63;
    const int c0 = lane, c1 = lane + 64;
    for (int i = t; i < (ADY*256)/8; i += 256) ((uint4*)sWf)[i] = ((const uint4*)Wf2)[i];
    float b_sc0 = bf2f(bf2v[c0]),       b_sc1 = bf2f(bf2v[c1]);
    float b_sh0 = bf2f(bf2v[128 + c0]), b_sh1 = bf2f(bf2v[128 + c1]);
    __syncthreads();
    for (int n = blockIdx.x*4 + wid; n < N_NODES; n += 2500) {
        float x0 = ldg1<F32>(out, (size_t)n*HID + c0);
        float x1 = ldg1<F32>(out, (size_t)n*HID + c1);
        float s = x0 + x1, q = x0*x0 + x1*x1;
        for (int off = 32; off > 0; off >>= 1) { s += __shfl_xor(s, off); q += __shfl_xor(q, off); }
        float mu   = s * (1.f/128.f);
        float var  = q * (1.f/128.f) - mu*mu;
        float rstd = rsqrtf(fmaxf(var, 0.f) + 1e-5f);
        float yv = ldg1<F32>(y, (size_t)n*ADY + lane);
        float f_sc0 = b_sc0, f_sc1 = b_sc1, f_sh0 = b_sh0, f_sh1 = b_sh1;
        for (int k = 0; k < 64; k++) {
            float yk = __shfl(yv, k);
            f_sc0 += yk * bf2f(sWf[k*256 + c0]);
            f_sc1 += yk * bf2f(sWf[k*256 + c1]);
            f_sh0 += yk * bf2f(sWf[k*256 + 128 + c0]);
            f_sh1 += yk * bf2f(sWf[k*256 + 128 + c1]);
        }
        stg1<F32>(out, (size_t)n*HID + c0, (x0 - mu)*rstd*(1.f + f_sc0) + f_sh0);
        stg1<F32>(out, (size_t)n*HID + c1, (x1 - mu)*rstd*(1.f + f_sc1) + f_sh1);
    }
}

__global__ __launch_bounds__(256, 1)
void node3_kernel(const int* __restrict__ flag, const void* y,
                  const u16* __restrict__ Wf2, const u16* __restrict__ bf2v,
                  void* out)
{
    __shared__ __align__(16) u16 sWf[ADY * 256];
    if (*flag) node3_body<true>(y, Wf2, bf2v, out, sWf);
    else       node3_body<false>(y, Wf2, bf2v, out, sWf);
}

// ---------------------------------------------------------------------------
extern "C" void kernel_launch(void* const* d_in, const int* in_sizes, int n_in,
                              void* d_out, int out_size, void* d_ws, size_t ws_size,
                              hipStream_t stream)
{
    const void* h      = d_in[0];
    const void* coords = d_in[1];
    const void* a      = d_in[2];
    const void* y      = d_in[3];
    const void* res    = d_in[4];
    const int* src     = (const int*)d_in[5];
    const int* dst     = (const int*)d_in[6];

    char* ws = (char*)d_ws;
    int*   flag = (int*)(ws + FLAG_OFF);
    float* den  = (float*)(ws + DEN_OFF);
    float* cacc = (float*)(ws + CACC_OFF);
    float* hagg = (float*)(ws + HAGG_OFF);
    u16*   tws  = (u16*)(ws + TWS_OFF);     // aliases hagg (dead after node1)

    // canonical bf16 weights in ws
    const int wn[16]  = {43680, 25600, 20480, 1280, 160, 160, 160, 16384,
                         20480, 160, 20480, 128, 16384, 256, 16384, 256};
    const int widx[16] = {7, 9, 12, 13, 11, 8, 10, 14, 15, 16, 17, 18, 19, 20, 21, 22};
    //                     We1 We2 Wv  Wa  Wc be1 be2 Wo Wn1 bn1 Wn2 bn2 Wf1 bf1 Wf2 bf2
    u64 off = CW_BASE;
    CvtArgs args;
    u64 offs[16];
    for (int i = 0; i < 16; i++) {
        args.src[i] = d_in[widx[i]];
        args.dstoff[i] = off;
        args.n[i] = wn[i];
        offs[i] = off;
        off += (u64)wn[i] * 2;
    }
    const u16* cWe1 = (const u16*)(ws + offs[0]);
    const u16* cWe2 = (const u16*)(ws + offs[1]);
    const u16* cWv  = (const u16*)(ws + offs[2]);
    const u16* cWa  = (const u16*)(ws + offs[3]);
    const u16* cWc  = (const u16*)(ws + offs[4]);
    const u16* cbe1 = (const u16*)(ws + offs[5]);
    const u16* cbe2 = (const u16*)(ws + offs[6]);
    const u16* cWo  = (const u16*)(ws + offs[7]);
    const u16* cWn1 = (const u16*)(ws + offs[8]);
    const u16* cbn1 = (const u16*)(ws + offs[9]);
    const u16* cWn2 = (const u16*)(ws + offs[10]);
    const u16* cbn2 = (const u16*)(ws + offs[11]);
    const u16* cWf1 = (const u16*)(ws + offs[12]);
    const u16* cbf1 = (const u16*)(ws + offs[13]);
    const u16* cWf2 = (const u16*)(ws + offs[14]);
    const u16* cbf2 = (const u16*)(ws + offs[15]);

    hipMemsetAsync(d_ws, 0, MEMSET_BYTES, stream);

    detect_kernel<<<1, 256, 0, stream>>>(h, flag);
    cvt_kernel<<<dim3(8, 16), 256, 0, stream>>>(flag, ws, args);

    edge_kernel<<<1024, 256, 0, stream>>>(flag, h, coords, a, src, dst,
                                          cWe1, cbe1, cWe2, cbe2, cWc, cWv, cWa,
                                          den, hagg, cacc);
    node1_kernel<<<625, 256, 0, stream>>>(flag, h, res, coords, y,
                                          cWo, cWf1, cbf1, den, hagg, cacc, d_out);
    node2a_kernel<<<625, 256, 0, stream>>>(flag, d_out, cWn1, cbn1, tws);
    node2b_kernel<<<625, 256, 0, stream>>>(flag, d_out, tws, cWn2, cbn2);
    node3_kernel<<<625, 256, 0, stream>>>(flag, y, cWf2, cbf2, d_out);
}

// Round 4
// 1394.016 us; speedup vs baseline: 2.1697x; 2.1697x over previous
//
#include <hip/hip_runtime.h>
#include <math.h>

#define N_NODES 25000
#define N_EDGES 400000
#define HID 128
#define EDGE_F 16
#define ADY 64
#define INNER 160
#define MSG_F 273
#define HEADS 8

// element offsets inside d_out (h2 | coords | res2)
#define OUT_CRD (N_NODES * HID)
#define OUT_RES (N_NODES * (HID + 3))

// ws byte offsets (16-aligned)
#define FLAG_OFF 0
#define DEN_OFF  256
#define CACC_OFF 800256
#define HAGG_OFF 1100288
#define TWS_OFF  HAGG_OFF            // aliases hagg (dead after node1)
#define CW_BASE  13900288            // canonical bf16 flat weights
#define MEMSET_BYTES 13900288

typedef unsigned short u16;
typedef unsigned int u32;
typedef unsigned long long u64;
typedef __attribute__((ext_vector_type(8))) short short8;
typedef __attribute__((ext_vector_type(4))) float f32x4;

__device__ __forceinline__ float bf2f(u16 v) {
    union { u32 u; float f; } x; x.u = ((u32)v) << 16; return x.f;
}
__device__ __forceinline__ u16 f2bf(float f) {
    union { float ff; u32 u; } x; x.ff = f;
    u32 u = x.u;
    u32 rounding = 0x7FFFu + ((u >> 16) & 1u);
    u += rounding;
    return (u16)(u >> 16);
}
__device__ __forceinline__ float silu(float z) {
    z = fminf(fmaxf(z, -30000.f), 30000.f);
    return z / (1.0f + __expf(-z));
}

template<bool F32> __device__ __forceinline__ float ldg1(const void* p, size_t i) {
    if (F32) return ((const float*)p)[i];
    return bf2f(((const u16*)p)[i]);
}
template<bool F32> __device__ __forceinline__ void stg1(void* p, size_t i, float v) {
    if (F32) ((float*)p)[i] = v;
    else     ((u16*)p)[i] = f2bf(v);
}
// 8 contiguous elements -> bf16 into 16B-aligned dst
template<bool F32> __device__ __forceinline__ void ld8a(const void* p, size_t i, u16* dst) {
    if (F32) {
        const float* fp = (const float*)p + i;
        float4 v0 = ((const float4*)fp)[0];
        float4 v1 = ((const float4*)fp)[1];
        __align__(16) u16 tmp[8] = { f2bf(v0.x), f2bf(v0.y), f2bf(v0.z), f2bf(v0.w),
                                     f2bf(v1.x), f2bf(v1.y), f2bf(v1.z), f2bf(v1.w) };
        *(uint4*)dst = *(const uint4*)tmp;
    } else {
        *(uint4*)dst = *(const uint4*)((const u16*)p + i);
    }
}
__device__ __forceinline__ float ldany(const void* p, size_t i, bool f32) {
    return f32 ? ((const float*)p)[i] : bf2f(((const u16*)p)[i]);
}

// ---------------------------------------------------------------------------
// dtype detector (flag=1 -> fp32 inputs)
// ---------------------------------------------------------------------------
__global__ void detect_kernel(const void* h, int* flag) {
    __shared__ float red[256];
    const int t = threadIdx.x;
    const u16* p = (const u16*)h;
    float mx = 0.f;
    for (int i = 0; i < 64; i++) {
        int idx = (t * 64 + i) * 97;
        float v = fabsf(bf2f(p[idx * 2]));
        mx = fmaxf(mx, v);
    }
    red[t] = mx;
    __syncthreads();
    for (int s = 128; s > 0; s >>= 1) {
        if (t < s) red[t] = fmaxf(red[t], red[t + s]);
        __syncthreads();
    }
    if (t == 0) flag[0] = (red[0] > 1e10f || red[0] == 0.f) ? 1 : 0;
}

// ---------------------------------------------------------------------------
// flat weight canonicalization: 16 tensors -> bf16 copies in ws
// ---------------------------------------------------------------------------
struct CvtArgs {
    const void* src[16];
    u64 dstoff[16];
    int n[16];
};
__global__ void cvt_kernel(const int* __restrict__ flag, char* wsbase, CvtArgs args) {
    const int ten = blockIdx.y;
    const void* s = args.src[ten];
    u16* d = (u16*)(wsbase + args.dstoff[ten]);
    const int n = args.n[ten];
    const bool f32 = (*flag != 0);
    if (f32) {
        const float* sf = (const float*)s;
        for (int i = blockIdx.x * 256 + threadIdx.x; i < n; i += gridDim.x * 256)
            d[i] = f2bf(sf[i]);
    } else {
        const u16* su = (const u16*)s;
        for (int i = blockIdx.x * 256 + threadIdx.x; i < n; i += gridDim.x * 256)
            d[i] = su[i];
    }
}

// ---------------------------------------------------------------------------
// blocked/transposed weight builder for MFMA edge kernel.
// We1T_b[5][160][72]: [c][n][kc] = We1[k][n], k=c*64+kc (k==273 slot repeats
//   row 256 for the radial-lo duplicate; zeros elsewhere/pad)
// We2T_b[3][160][72]: [c][n][kc] = We2[c*64+kc][n]
// W3T_b [3][144][72]: cols n<128 Wv, n in[128,136) Wa, n==136 Wc, else 0
// ---------------------------------------------------------------------------
__global__ void blockw_kernel(const int* __restrict__ flag, char* ws,
                              u64 b1off, u64 b2off, u64 b3off,
                              const void* We1, const void* We2,
                              const void* Wv, const void* Wa, const void* Wc)
{
    const bool f32 = (*flag != 0);
    u16* b1 = (u16*)(ws + b1off);
    u16* b2 = (u16*)(ws + b2off);
    u16* b3 = (u16*)(ws + b3off);
    const int g = blockIdx.x * 256 + threadIdx.x;
    const int stride = gridDim.x * 256;
    for (int i = g; i < 5*160*72; i += stride) {
        int c = i / (160*72), rem = i % (160*72), n = rem / 72, kc = rem % 72;
        int k = c*64 + kc;
        float v = 0.f;
        if (kc < 64) {
            if (k < MSG_F)      v = ldany(We1, (size_t)k*INNER + n, f32);
            else if (k == 273)  v = ldany(We1, (size_t)256*INNER + n, f32);
        }
        b1[i] = f2bf(v);
    }
    for (int i = g; i < 3*160*72; i += stride) {
        int c = i / (160*72), rem = i % (160*72), n = rem / 72, kc = rem % 72;
        int k = c*64 + kc;
        float v = 0.f;
        if (kc < 64 && k < INNER) v = ldany(We2, (size_t)k*INNER + n, f32);
        b2[i] = f2bf(v);
    }
    for (int i = g; i < 3*144*72; i += stride) {
        int c = i / (144*72), rem = i % (144*72), n = rem / 72, kc = rem % 72;
        int k = c*64 + kc;
        float v = 0.f;
        if (kc < 64 && k < INNER) {
            if (n < 128)      v = ldany(Wv, (size_t)k*HID + n, f32);
            else if (n < 136) v = ldany(Wa, (size_t)k*HEADS + (n-128), f32);
            else if (n == 136) v = ldany(Wc, (size_t)k, f32);
        }
        b3[i] = f2bf(v);
    }
}

// ---------------------------------------------------------------------------
// MFMA edge kernel. 64 edges/tile, 4 waves; wave w owns edges [16w,16w+16).
// GEMM1: f[64x320-pad] @ We1[320x160]; GEMM2: m1 @ We2[160x160];
// GEMM3: m2 @ [Wv|Wa|Wc][160x144-pad]. C->A transform via LDS round trip.
// Epilogue: exp/atomics identical to scalar version.
// ---------------------------------------------------------------------------
template<bool F32>
__device__ __forceinline__ void edge_body(
    const void* h, const void* coords, const void* a,
    const int* __restrict__ src, const int* __restrict__ dst,
    const u16* __restrict__ We1Tb, const u16* __restrict__ We2Tb,
    const u16* __restrict__ W3Tb,
    const u16* __restrict__ cbe1, const u16* __restrict__ cbe2,
    float* __restrict__ den, float* __restrict__ hagg, float* __restrict__ cacc,
    u16* sB, u16* sF, u16* sM1, u16* sM2,
    float* sex, float* sdiff, float* srad, int* ssrc, int* sdstl)
{
    const int t   = threadIdx.x;
    const int w   = t >> 6;
    const int l   = t & 63;
    const int col = l & 15;   // MFMA: A-row / B-col / C-col index
    const int q   = l >> 4;   // quad

    float bias1[10], bias2[10];
    #pragma unroll
    for (int nt = 0; nt < 10; nt++) {
        bias1[nt] = bf2f(cbe1[nt*16 + col]);
        bias2[nt] = bf2f(cbe2[nt*16 + col]);
    }

    for (int tile = blockIdx.x; tile < N_EDGES/64; tile += gridDim.x) {
        const int e0 = tile * 64;
        __syncthreads();   // prev tile fully done
        if (t < 64) {
            int e = e0 + t;
            int s = src[e], d = dst[e];
            ssrc[t] = s; sdstl[t] = d;
            float dx = ldg1<F32>(coords, (size_t)s*3+0) - ldg1<F32>(coords, (size_t)d*3+0);
            float dy = ldg1<F32>(coords, (size_t)s*3+1) - ldg1<F32>(coords, (size_t)d*3+1);
            float dz = ldg1<F32>(coords, (size_t)s*3+2) - ldg1<F32>(coords, (size_t)d*3+2);
            sdiff[t*4+0] = dx; sdiff[t*4+1] = dy; sdiff[t*4+2] = dz;
            float r2 = dx*dx + dy*dy + dz*dz;
            srad[t] = r2;
            sdiff[t*4+3] = 1.0f / (sqrtf(r2 + 1e-5f) + 1.0f);
        }
        __syncthreads();

        // ================= GEMM1: K=320 in 5 chunks of 64 =================
        f32x4 acc1[10];
        #pragma unroll
        for (int nt = 0; nt < 10; nt++)
            acc1[nt] = (f32x4){bias1[nt], bias1[nt], bias1[nt], bias1[nt]};

        for (int c = 0; c < 5; c++) {
            {   // stage B chunk: 160x72 bf16 = 1440 uint4
                const uint4* g4 = (const uint4*)(We1Tb + (size_t)c*160*72);
                uint4* s4 = (uint4*)sB;
                for (int i = t; i < 1440; i += 256) s4[i] = g4[i];
            }
            {   // stage F chunk: 64 edges x 64 k
                int e = t >> 2, part = t & 3;
                if (c < 4) {
                    int node = (c < 2) ? ssrc[e] : sdstl[e];
                    int c0 = (c & 1) * 64 + part * 16;
                    ld8a<F32>(h, (size_t)node*HID + c0,     &sF[e*72 + part*16]);
                    ld8a<F32>(h, (size_t)node*HID + c0 + 8, &sF[e*72 + part*16 + 8]);
                } else {
                    __align__(16) u16 tmp[16];
                    #pragma unroll
                    for (int j = 0; j < 16; j++) tmp[j] = 0;
                    if (part == 0) {
                        float r2 = srad[e];
                        tmp[0] = f2bf(r2);                       // kc0 = radial hi
                        for (int j = 0; j < 15; j++)             // kc1..15 = a[0..14]
                            tmp[1+j] = f2bf(ldg1<F32>(a, (size_t)(e0+e)*EDGE_F + j));
                    } else if (part == 1) {
                        tmp[0] = f2bf(ldg1<F32>(a, (size_t)(e0+e)*EDGE_F + 15)); // kc16
                        float r2 = srad[e];
                        tmp[1] = f2bf(r2 - bf2f(f2bf(r2)));      // kc17 = radial lo
                    }
                    *(uint4*)(&sF[e*72 + part*16])     = ((uint4*)tmp)[0];
                    *(uint4*)(&sF[e*72 + part*16 + 8]) = ((uint4*)tmp)[1];
                }
            }
            __syncthreads();
            const u16* fbase = &sF[(w*16 + col)*72];
            #pragma unroll
            for (int ks = 0; ks < 2; ks++) {
                short8 af = *(const short8*)(fbase + ks*32 + q*8);
                #pragma unroll
                for (int nt = 0; nt < 10; nt++) {
                    short8 bfr = *(const short8*)(&sB[(nt*16 + col)*72 + ks*32 + q*8]);
                    acc1[nt] = __builtin_amdgcn_mfma_f32_16x16x32_bf16(af, bfr, acc1[nt], 0, 0, 0);
                }
            }
            __syncthreads();
        }
        // silu -> sM1 (C-layout scatter: row = w*16+q*4+r, col = nt*16+col)
        #pragma unroll
        for (int nt = 0; nt < 10; nt++)
            #pragma unroll
            for (int r = 0; r < 4; r++)
                sM1[(w*16 + q*4 + r)*168 + nt*16 + col] = f2bf(silu(acc1[nt][r]));

        // ================= GEMM2: K=160 in chunks {64,64,32} ==============
        f32x4 acc2[10];
        #pragma unroll
        for (int nt = 0; nt < 10; nt++)
            acc2[nt] = (f32x4){bias2[nt], bias2[nt], bias2[nt], bias2[nt]};

        for (int c = 0; c < 3; c++) {
            {
                const uint4* g4 = (const uint4*)(We2Tb + (size_t)c*160*72);
                uint4* s4 = (uint4*)sB;
                for (int i = t; i < 1440; i += 256) s4[i] = g4[i];
            }
            __syncthreads();
            const int nks = (c < 2) ? 2 : 1;
            for (int ks = 0; ks < nks; ks++) {
                short8 af = *(const short8*)(&sM1[(w*16 + col)*168 + c*64 + ks*32 + q*8]);
                #pragma unroll
                for (int nt = 0; nt < 10; nt++) {
                    short8 bfr = *(const short8*)(&sB[(nt*16 + col)*72 + ks*32 + q*8]);
                    acc2[nt] = __builtin_amdgcn_mfma_f32_16x16x32_bf16(af, bfr, acc2[nt], 0, 0, 0);
                }
            }
            __syncthreads();
        }
        #pragma unroll
        for (int nt = 0; nt < 10; nt++)
            #pragma unroll
            for (int r = 0; r < 4; r++)
                sM2[(w*16 + q*4 + r)*168 + nt*16 + col] = f2bf(silu(acc2[nt][r]));

        // ================= GEMM3: m2 @ W3 (N=144), K=160 ==================
        f32x4 acc3[9];
        #pragma unroll
        for (int nt = 0; nt < 9; nt++) acc3[nt] = (f32x4){0.f, 0.f, 0.f, 0.f};

        for (int c = 0; c < 3; c++) {
            {
                const uint4* g4 = (const uint4*)(W3Tb + (size_t)c*144*72);
                uint4* s4 = (uint4*)sB;
                for (int i = t; i < 1296; i += 256) s4[i] = g4[i];
            }
            __syncthreads();
            const int nks = (c < 2) ? 2 : 1;
            for (int ks = 0; ks < nks; ks++) {
                short8 af = *(const short8*)(&sM2[(w*16 + col)*168 + c*64 + ks*32 + q*8]);
                #pragma unroll
                for (int nt = 0; nt < 9; nt++) {
                    short8 bfr = *(const short8*)(&sB[(nt*16 + col)*72 + ks*32 + q*8]);
                    acc3[nt] = __builtin_amdgcn_mfma_f32_16x16x32_bf16(af, bfr, acc3[nt], 0, 0, 0);
                }
            }
            __syncthreads();
        }

        // ================= epilogue: heads + atomics ======================
        const int mbase = w*16 + q*4;
        if (col < 8) {          // logits: head = col, cols 128..135
            #pragma unroll
            for (int r = 0; r < 4; r++) {
                int m = mbase + r;
                int d = sdstl[m];
                float ex = __expf(fminf(fmaxf(acc3[8][r], -30.f), 30.f));
                sex[m*8 + col] = ex;
                atomicAdd(&den[(size_t)d*8 + col], ex);
            }
        } else if (col == 8) {  // coord scalar: col 136
            #pragma unroll
            for (int r = 0; r < 4; r++) {
                int m = mbase + r;
                int d = sdstl[m];
                float lc = fminf(fmaxf(acc3[8][r], -1e6f), 1e6f);
                float invf = sdiff[m*4 + 3];
                #pragma unroll
                for (int j = 0; j < 3; j++)
                    atomicAdd(&cacc[(size_t)d*3 + j], lc * sdiff[m*4 + j] * invf);
            }
        }
        __syncthreads();        // sex visible
        #pragma unroll
        for (int nt = 0; nt < 8; nt++) {
            #pragma unroll
            for (int r = 0; r < 4; r++) {
                int m = mbase + r;
                int d = sdstl[m];
                atomicAdd(&hagg[(size_t)d*HID + nt*16 + col], acc3[nt][r] * sex[m*8 + nt]);
            }
        }
    }
}

__global__ __launch_bounds__(256, 2)
void edge_kernel(const int* __restrict__ flag,
                 const void* h, const void* coords, const void* a,
                 const int* __restrict__ src, const int* __restrict__ dst,
                 const u16* __restrict__ We1Tb, const u16* __restrict__ We2Tb,
                 const u16* __restrict__ W3Tb,
                 const u16* __restrict__ cbe1, const u16* __restrict__ cbe2,
                 float* __restrict__ den, float* __restrict__ hagg,
                 float* __restrict__ cacc)
{
    __shared__ __align__(16) u16 sB[160*72];    // 23040 B
    __shared__ __align__(16) u16 sF[64*72];     //  9216 B
    __shared__ __align__(16) u16 sM1[64*168];   // 21504 B
    __shared__ __align__(16) u16 sM2[64*168];   // 21504 B
    __shared__ float sex[64*8];
    __shared__ float sdiff[64*4];
    __shared__ float srad[64];
    __shared__ int   ssrc[64];
    __shared__ int   sdstl[64];
    if (*flag)
        edge_body<true>(h, coords, a, src, dst, We1Tb, We2Tb, W3Tb, cbe1, cbe2,
                        den, hagg, cacc, sB, sF, sM1, sM2, sex, sdiff, srad, ssrc, sdstl);
    else
        edge_body<false>(h, coords, a, src, dst, We1Tb, We2Tb, W3Tb, cbe1, cbe2,
                         den, hagg, cacc, sB, sF, sM1, sM2, sex, sdiff, srad, ssrc, sdstl);
}

// ---------------------------------------------------------------------------
// node1: h_agg = hagg/den; f2 = h_agg@Wo; res1 = res+f2 -> out_res slot;
// h1 = adaLN(h+f2, FiLM1(y)) -> out h2 slot; coords_out = coords + cacc.
// ---------------------------------------------------------------------------
template<bool F32>
__device__ __forceinline__ void node1_body(
    const void* h, const void* res, const void* coords, const void* y,
    const u16* __restrict__ Wo, const u16* __restrict__ Wf1,
    const u16* __restrict__ bf1v,
    const float* __restrict__ den, const float* __restrict__ hagg,
    const float* __restrict__ cacc, void* out, u16* sWo, u16* sWf)
{
    const int t = threadIdx.x, wid = t >> 6, lane = t & 63;
    const int c0 = lane, c1 = lane + 64;
    for (int i = t; i < (HID*HID)/8; i += 256) ((uint4*)sWo)[i] = ((const uint4*)Wo)[i];
    for (int i = t; i < (ADY*256)/8; i += 256) ((uint4*)sWf)[i] = ((const uint4*)Wf1)[i];
    float b_sc0 = bf2f(bf1v[c0]),       b_sc1 = bf2f(bf1v[c1]);
    float b_sh0 = bf2f(bf1v[128 + c0]), b_sh1 = bf2f(bf1v[128 + c1]);
    __syncthreads();
    for (int n = blockIdx.x*4 + wid; n < N_NODES; n += 2500) {
        float dd0 = den[(size_t)n*8 + (c0 >> 4)];
        float dd1 = den[(size_t)n*8 + (c1 >> 4)];
        float g0 = dd0 > 0.f ? hagg[(size_t)n*HID + c0] / dd0 : 0.f;
        float g1 = dd1 > 0.f ? hagg[(size_t)n*HID + c1] / dd1 : 0.f;
        float f20 = 0.f, f21 = 0.f;
        for (int k = 0; k < 64; k++) {
            float hk = __shfl(g0, k);
            f20 += hk * bf2f(sWo[k*HID + c0]);
            f21 += hk * bf2f(sWo[k*HID + c1]);
        }
        for (int k = 0; k < 64; k++) {
            float hk = __shfl(g1, k);
            f20 += hk * bf2f(sWo[(k+64)*HID + c0]);
            f21 += hk * bf2f(sWo[(k+64)*HID + c1]);
        }
        stg1<F32>(out, (size_t)OUT_RES + (size_t)n*HID + c0,
                  ldg1<F32>(res, (size_t)n*HID + c0) + f20);
        stg1<F32>(out, (size_t)OUT_RES + (size_t)n*HID + c1,
                  ldg1<F32>(res, (size_t)n*HID + c1) + f21);
        float x0 = ldg1<F32>(h, (size_t)n*HID + c0) + f20;
        float x1 = ldg1<F32>(h, (size_t)n*HID + c1) + f21;
        float s = x0 + x1, qq = x0*x0 + x1*x1;
        for (int off = 32; off > 0; off >>= 1) { s += __shfl_xor(s, off); qq += __shfl_xor(qq, off); }
        float mu   = s * (1.f/128.f);
        float var  = qq * (1.f/128.f) - mu*mu;
        float rstd = rsqrtf(fmaxf(var, 0.f) + 1e-5f);
        float yv = ldg1<F32>(y, (size_t)n*ADY + lane);
        float f_sc0 = b_sc0, f_sc1 = b_sc1, f_sh0 = b_sh0, f_sh1 = b_sh1;
        for (int k = 0; k < 64; k++) {
            float yk = __shfl(yv, k);
            f_sc0 += yk * bf2f(sWf[k*256 + c0]);
            f_sc1 += yk * bf2f(sWf[k*256 + c1]);
            f_sh0 += yk * bf2f(sWf[k*256 + 128 + c0]);
            f_sh1 += yk * bf2f(sWf[k*256 + 128 + c1]);
        }
        stg1<F32>(out, (size_t)n*HID + c0, (x0 - mu)*rstd*(1.f + f_sc0) + f_sh0);
        stg1<F32>(out, (size_t)n*HID + c1, (x1 - mu)*rstd*(1.f + f_sc1) + f_sh1);
        if (lane < 3)
            stg1<F32>(out, (size_t)OUT_CRD + (size_t)n*3 + lane,
                      ldg1<F32>(coords, (size_t)n*3 + lane) + cacc[(size_t)n*3 + lane]);
    }
}

__global__ __launch_bounds__(256, 1)
void node1_kernel(const int* __restrict__ flag,
                  const void* h, const void* res, const void* coords, const void* y,
                  const u16* __restrict__ Wo, const u16* __restrict__ Wf1,
                  const u16* __restrict__ bf1v,
                  const float* __restrict__ den, const float* __restrict__ hagg,
                  const float* __restrict__ cacc, void* out)
{
    __shared__ __align__(16) u16 sWo[HID * HID];
    __shared__ __align__(16) u16 sWf[ADY * 256];
    if (*flag) node1_body<true>(h, res, coords, y, Wo, Wf1, bf1v, den, hagg, cacc, out, sWo, sWf);
    else       node1_body<false>(h, res, coords, y, Wo, Wf1, bf1v, den, hagg, cacc, out, sWo, sWf);
}

// ---------------------------------------------------------------------------
// node2a: t = silu(h1 @ Wn1 + bn1) -> tws (bf16)
// ---------------------------------------------------------------------------
template<bool F32>
__device__ __forceinline__ void node2a_body(
    const void* out, const u16* __restrict__ Wn1, const u16* __restrict__ bn1,
    u16* __restrict__ tws, u16* sW, float* sb)
{
    const int t = threadIdx.x, wid = t >> 6, lane = t & 63;
    for (int i = t; i < (HID*INNER)/8; i += 256) ((uint4*)sW)[i] = ((const uint4*)Wn1)[i];
    for (int i = t; i < INNER; i += 256) sb[i] = bf2f(bn1[i]);
    __syncthreads();
    for (int n = blockIdx.x*4 + wid; n < N_NODES; n += 2500) {
        float a0 = ldg1<F32>(out, (size_t)n*HID + lane);
        float a1 = ldg1<F32>(out, (size_t)n*HID + 64 + lane);
        const int c0 = lane, c1 = lane + 64, c2 = lane + 128;
        float t0 = sb[c0], t1 = sb[c1], t2 = (lane < 32) ? sb[c2] : 0.f;
        for (int k = 0; k < 64; k++) {
            float hk = __shfl(a0, k);
            t0 += hk * bf2f(sW[k*INNER + c0]);
            t1 += hk * bf2f(sW[k*INNER + c1]);
            if (lane < 32) t2 += hk * bf2f(sW[k*INNER + c2]);
        }
        for (int k = 0; k < 64; k++) {
            float hk = __shfl(a1, k);
            t0 += hk * bf2f(sW[(k+64)*INNER + c0]);
            t1 += hk * bf2f(sW[(k+64)*INNER + c1]);
            if (lane < 32) t2 += hk * bf2f(sW[(k+64)*INNER + c2]);
        }
        tws[(size_t)n*INNER + c0] = f2bf(silu(t0));
        tws[(size_t)n*INNER + c1] = f2bf(silu(t1));
        if (lane < 32) tws[(size_t)n*INNER + c2] = f2bf(silu(t2));
    }
}

__global__ __launch_bounds__(256, 1)
void node2a_kernel(const int* __restrict__ flag, const void* out,
                   const u16* __restrict__ Wn1, const u16* __restrict__ bn1,
                   u16* __restrict__ tws)
{
    __shared__ __align__(16) u16 sW[HID * INNER];
    __shared__ float sb[INNER];
    if (*flag) node2a_body<true>(out, Wn1, bn1, tws, sW, sb);
    else       node2a_body<false>(out, Wn1, bn1, tws, sW, sb);
}

// ---------------------------------------------------------------------------
// node2b: f3 = t @ Wn2 + bn2; res2 = res1 + f3; x2 = h1 + f3 (both rmw in out)
// ---------------------------------------------------------------------------
template<bool F32>
__device__ __forceinline__ void node2b_body(
    void* out, const u16* __restrict__ tws,
    const u16* __restrict__ Wn2, const u16* __restrict__ bn2,
    u16* sW, float* sb)
{
    const int t = threadIdx.x, wid = t >> 6, lane = t & 63;
    for (int i = t; i < (INNER*HID)/8; i += 256) ((uint4*)sW)[i] = ((const uint4*)Wn2)[i];
    for (int i = t; i < HID; i += 256) sb[i] = bf2f(bn2[i]);
    __syncthreads();
    for (int n = blockIdx.x*4 + wid; n < N_NODES; n += 2500) {
        float b0 = bf2f(tws[(size_t)n*INNER + lane]);
        float b1 = bf2f(tws[(size_t)n*INNER + 64 + lane]);
        float b2 = (lane < 32) ? bf2f(tws[(size_t)n*INNER + 128 + lane]) : 0.f;
        const int c0 = lane, c1 = lane + 64;
        float f0 = sb[c0], f1 = sb[c1];
        for (int k = 0; k < 64; k++) { float tk = __shfl(b0, k); f0 += tk*bf2f(sW[k*HID + c0]);       f1 += tk*bf2f(sW[k*HID + c1]); }
        for (int k = 0; k < 64; k++) { float tk = __shfl(b1, k); f0 += tk*bf2f(sW[(k+64)*HID + c0]);  f1 += tk*bf2f(sW[(k+64)*HID + c1]); }
        for (int k = 0; k < 32; k++) { float tk = __shfl(b2, k); f0 += tk*bf2f(sW[(k+128)*HID + c0]); f1 += tk*bf2f(sW[(k+128)*HID + c1]); }
        stg1<F32>(out, (size_t)OUT_RES + (size_t)n*HID + c0,
                  ldg1<F32>(out, (size_t)OUT_RES + (size_t)n*HID + c0) + f0);
        stg1<F32>(out, (size_t)OUT_RES + (size_t)n*HID + c1,
                  ldg1<F32>(out, (size_t)OUT_RES + (size_t)n*HID + c1) + f1);
        stg1<F32>(out, (size_t)n*HID + c0, ldg1<F32>(out, (size_t)n*HID + c0) + f0);
        stg1<F32>(out, (size_t)n*HID + c1, ldg1<F32>(out, (size_t)n*HID + c1) + f1);
    }
}

__global__ __launch_bounds__(256, 1)
void node2b_kernel(const int* __restrict__ flag, void* out,
                   const u16* __restrict__ tws,
                   const u16* __restrict__ Wn2, const u16* __restrict__ bn2)
{
    __shared__ __align__(16) u16 sW[INNER * HID];
    __shared__ float sb[HID];
    if (*flag) node2b_body<true>(out, tws, Wn2, bn2, sW, sb);
    else       node2b_body<false>(out, tws, Wn2, bn2, sW, sb);
}

// ---------------------------------------------------------------------------
// node3: h2 = adaLN(x2, FiLM2(y)) in place over out h2 slot.
// ---------------------------------------------------------------------------
template<bool F32>
__device__ __forceinline__ void node3_body(
    const void* y, const u16* __restrict__ Wf2, const u16* __restrict__ bf2v,
    void* out, u16* sWf)
{
    const int t = threadIdx.x, wid = t >> 6, lane = t & 63;
    const int c0 = lane, c1 = lane + 64;
    for (int i = t; i < (ADY*256)/8; i += 256) ((uint4*)sWf)[i] = ((const uint4*)Wf2)[i];
    float b_sc0 = bf2f(bf2v[c0]),       b_sc1 = bf2f(bf2v[c1]);
    float b_sh0 = bf2f(bf2v[128 + c0]), b_sh1 = bf2f(bf2v[128 + c1]);
    __syncthreads();
    for (int n = blockIdx.x*4 + wid; n < N_NODES; n += 2500) {
        float x0 = ldg1<F32>(out, (size_t)n*HID + c0);
        float x1 = ldg1<F32>(out, (size_t)n*HID + c1);
        float s = x0 + x1, qq = x0*x0 + x1*x1;
        for (int off = 32; off > 0; off >>= 1) { s += __shfl_xor(s, off); qq += __shfl_xor(qq, off); }
        float mu   = s * (1.f/128.f);
        float var  = qq * (1.f/128.f) - mu*mu;
        float rstd = rsqrtf(fmaxf(var, 0.f) + 1e-5f);
        float yv = ldg1<F32>(y, (size_t)n*ADY + lane);
        float f_sc0 = b_sc0, f_sc1 = b_sc1, f_sh0 = b_sh0, f_sh1 = b_sh1;
        for (int k = 0; k < 64; k++) {
            float yk = __shfl(yv, k);
            f_sc0 += yk * bf2f(sWf[k*256 + c0]);
            f_sc1 += yk * bf2f(sWf[k*256 + c1]);
            f_sh0 += yk * bf2f(sWf[k*256 + 128 + c0]);
            f_sh1 += yk * bf2f(sWf[k*256 + 128 + c1]);
        }
        stg1<F32>(out, (size_t)n*HID + c0, (x0 - mu)*rstd*(1.f + f_sc0) + f_sh0);
        stg1<F32>(out, (size_t)n*HID + c1, (x1 - mu)*rstd*(1.f + f_sc1) + f_sh1);
    }
}

__global__ __launch_bounds__(256, 1)
void node3_kernel(const int* __restrict__ flag, const void* y,
                  const u16* __restrict__ Wf2, const u16* __restrict__ bf2v,
                  void* out)
{
    __shared__ __align__(16) u16 sWf[ADY * 256];
    if (*flag) node3_body<true>(y, Wf2, bf2v, out, sWf);
    else       node3_body<false>(y, Wf2, bf2v, out, sWf);
}

// ---------------------------------------------------------------------------
extern "C" void kernel_launch(void* const* d_in, const int* in_sizes, int n_in,
                              void* d_out, int out_size, void* d_ws, size_t ws_size,
                              hipStream_t stream)
{
    const void* h      = d_in[0];
    const void* coords = d_in[1];
    const void* a      = d_in[2];
    const void* y      = d_in[3];
    const void* res    = d_in[4];
    const int* src     = (const int*)d_in[5];
    const int* dst     = (const int*)d_in[6];

    char* ws = (char*)d_ws;
    int*   flag = (int*)(ws + FLAG_OFF);
    float* den  = (float*)(ws + DEN_OFF);
    float* cacc = (float*)(ws + CACC_OFF);
    float* hagg = (float*)(ws + HAGG_OFF);
    u16*   tws  = (u16*)(ws + TWS_OFF);

    // flat canonical bf16 weights
    const int wn[16]  = {43680, 25600, 20480, 1280, 160, 160, 160, 16384,
                         20480, 160, 20480, 128, 16384, 256, 16384, 256};
    const int widx[16] = {7, 9, 12, 13, 11, 8, 10, 14, 15, 16, 17, 18, 19, 20, 21, 22};
    //                     We1 We2 Wv  Wa  Wc be1 be2 Wo Wn1 bn1 Wn2 bn2 Wf1 bf1 Wf2 bf2
    u64 off = CW_BASE;
    CvtArgs args;
    u64 offs[16];
    for (int i = 0; i < 16; i++) {
        args.src[i] = d_in[widx[i]];
        args.dstoff[i] = off;
        args.n[i] = wn[i];
        offs[i] = off;
        off += (u64)wn[i] * 2;
    }
    // blocked MFMA weights after flat ones
    u64 bw1 = (off + 255) & ~(u64)255;     // 5*160*72 bf16
    u64 bw2 = bw1 + (u64)5*160*72*2;       // 3*160*72
    u64 bw3 = bw2 + (u64)3*160*72*2;       // 3*144*72

    const u16* cbe1 = (const u16*)(ws + offs[5]);
    const u16* cbe2 = (const u16*)(ws + offs[6]);
    const u16* cWo  = (const u16*)(ws + offs[7]);
    const u16* cWn1 = (const u16*)(ws + offs[8]);
    const u16* cbn1 = (const u16*)(ws + offs[9]);
    const u16* cWn2 = (const u16*)(ws + offs[10]);
    const u16* cbn2 = (const u16*)(ws + offs[11]);
    const u16* cWf1 = (const u16*)(ws + offs[12]);
    const u16* cbf1 = (const u16*)(ws + offs[13]);
    const u16* cWf2 = (const u16*)(ws + offs[14]);
    const u16* cbf2 = (const u16*)(ws + offs[15]);
    const u16* We1Tb = (const u16*)(ws + bw1);
    const u16* We2Tb = (const u16*)(ws + bw2);
    const u16* W3Tb  = (const u16*)(ws + bw3);

    hipMemsetAsync(d_ws, 0, MEMSET_BYTES, stream);

    detect_kernel<<<1, 256, 0, stream>>>(h, flag);
    cvt_kernel<<<dim3(8, 16), 256, 0, stream>>>(flag, ws, args);
    blockw_kernel<<<64, 256, 0, stream>>>(flag, ws, bw1, bw2, bw3,
                                          d_in[7], d_in[9], d_in[12], d_in[13], d_in[11]);

    edge_kernel<<<512, 256, 0, stream>>>(flag, h, coords, a, src, dst,
                                         We1Tb, We2Tb, W3Tb, cbe1, cbe2,
                                         den, hagg, cacc);

    node1_kernel<<<625, 256, 0, stream>>>(flag, h, res, coords, y,
                                          cWo, cWf1, cbf1, den, hagg, cacc, d_out);
    node2a_kernel<<<625, 256, 0, stream>>>(flag, d_out, cWn1, cbn1, tws);
    node2b_kernel<<<625, 256, 0, stream>>>(flag, d_out, tws, cWn2, cbn2);
    node3_kernel<<<625, 256, 0, stream>>>(flag, y, cWf2, cbf2, d_out);
}

// Round 5
// 755.003 us; speedup vs baseline: 4.0061x; 1.8464x over previous
//
#include <hip/hip_runtime.h>
#include <math.h>

#define N_NODES 25000
#define N_EDGES 400000
#define HID 128
#define EDGE_F 16
#define ADY 64
#define INNER 160
#define MSG_F 273
#define HEADS 8

// element offsets inside d_out (h2 | coords | res2)
#define OUT_CRD (N_NODES * HID)
#define OUT_RES (N_NODES * (HID + 3))

// ws byte offsets (16-aligned)
#define FLAG_OFF 0
#define DEN_OFF  256
#define CACC_OFF 800256
#define HAGG_OFF 1100288
#define CW_BASE  13900288            // canonical bf16 flat weights
#define MEMSET_BYTES 13900288

typedef unsigned short u16;
typedef unsigned int u32;
typedef unsigned long long u64;
typedef __attribute__((ext_vector_type(8))) short short8;
typedef __attribute__((ext_vector_type(4))) float f32x4;

__device__ __forceinline__ float bf2f(u16 v) {
    union { u32 u; float f; } x; x.u = ((u32)v) << 16; return x.f;
}
__device__ __forceinline__ u16 f2bf(float f) {
    union { float ff; u32 u; } x; x.ff = f;
    u32 u = x.u;
    u32 rounding = 0x7FFFu + ((u >> 16) & 1u);
    u += rounding;
    return (u16)(u >> 16);
}
__device__ __forceinline__ float silu(float z) {
    z = fminf(fmaxf(z, -30000.f), 30000.f);
    return z / (1.0f + __expf(-z));
}

template<bool F32> __device__ __forceinline__ float ldg1(const void* p, size_t i) {
    if (F32) return ((const float*)p)[i];
    return bf2f(((const u16*)p)[i]);
}
template<bool F32> __device__ __forceinline__ void stg1(void* p, size_t i, float v) {
    if (F32) ((float*)p)[i] = v;
    else     ((u16*)p)[i] = f2bf(v);
}
template<bool F32> __device__ __forceinline__ void ld8a(const void* p, size_t i, u16* dst) {
    if (F32) {
        const float* fp = (const float*)p + i;
        float4 v0 = ((const float4*)fp)[0];
        float4 v1 = ((const float4*)fp)[1];
        __align__(16) u16 tmp[8] = { f2bf(v0.x), f2bf(v0.y), f2bf(v0.z), f2bf(v0.w),
                                     f2bf(v1.x), f2bf(v1.y), f2bf(v1.z), f2bf(v1.w) };
        *(uint4*)dst = *(const uint4*)tmp;
    } else {
        *(uint4*)dst = *(const uint4*)((const u16*)p + i);
    }
}
__device__ __forceinline__ float ldany(const void* p, size_t i, bool f32) {
    return f32 ? ((const float*)p)[i] : bf2f(((const u16*)p)[i]);
}

// ---------------------------------------------------------------------------
// dtype detector (flag=1 -> fp32 inputs)
// ---------------------------------------------------------------------------
__global__ void detect_kernel(const void* h, int* flag) {
    __shared__ float red[256];
    const int t = threadIdx.x;
    const u16* p = (const u16*)h;
    float mx = 0.f;
    for (int i = 0; i < 64; i++) {
        int idx = (t * 64 + i) * 97;
        float v = fabsf(bf2f(p[idx * 2]));
        mx = fmaxf(mx, v);
    }
    red[t] = mx;
    __syncthreads();
    for (int s = 128; s > 0; s >>= 1) {
        if (t < s) red[t] = fmaxf(red[t], red[t + s]);
        __syncthreads();
    }
    if (t == 0) flag[0] = (red[0] > 1e10f || red[0] == 0.f) ? 1 : 0;
}

// ---------------------------------------------------------------------------
// flat weight canonicalization: 16 tensors -> bf16 copies in ws
// ---------------------------------------------------------------------------
struct CvtArgs {
    const void* src[16];
    u64 dstoff[16];
    int n[16];
};
__global__ void cvt_kernel(const int* __restrict__ flag, char* wsbase, CvtArgs args) {
    const int ten = blockIdx.y;
    const void* s = args.src[ten];
    u16* d = (u16*)(wsbase + args.dstoff[ten]);
    const int n = args.n[ten];
    const bool f32 = (*flag != 0);
    if (f32) {
        const float* sf = (const float*)s;
        for (int i = blockIdx.x * 256 + threadIdx.x; i < n; i += gridDim.x * 256)
            d[i] = f2bf(sf[i]);
    } else {
        const u16* su = (const u16*)s;
        for (int i = blockIdx.x * 256 + threadIdx.x; i < n; i += gridDim.x * 256)
            d[i] = su[i];
    }
}

// ---------------------------------------------------------------------------
// blocked/transposed [n][72] weight builder for all MFMA GEMMs
// ---------------------------------------------------------------------------
__global__ void blockw_kernel(const int* __restrict__ flag, char* ws,
                              u64 b1off, u64 b2off, u64 b3off, u64 b4off,
                              u64 b5off, u64 b6off, u64 b7off, u64 b8off,
                              const void* We1, const void* We2,
                              const void* Wv, const void* Wa, const void* Wc,
                              const void* Wo, const void* Wn1, const void* Wn2,
                              const void* Wf1, const void* Wf2)
{
    const bool f32 = (*flag != 0);
    u16* b1 = (u16*)(ws + b1off);
    u16* b2 = (u16*)(ws + b2off);
    u16* b3 = (u16*)(ws + b3off);
    u16* b4 = (u16*)(ws + b4off);
    u16* b5 = (u16*)(ws + b5off);
    u16* b6 = (u16*)(ws + b6off);
    u16* b7 = (u16*)(ws + b7off);
    u16* b8 = (u16*)(ws + b8off);
    const int g = blockIdx.x * 256 + threadIdx.x;
    const int stride = gridDim.x * 256;
    for (int i = g; i < 5*160*72; i += stride) {
        int c = i / (160*72), rem = i % (160*72), n = rem / 72, kc = rem % 72;
        int k = c*64 + kc;
        float v = 0.f;
        if (kc < 64) {
            if (k < MSG_F)      v = ldany(We1, (size_t)k*INNER + n, f32);
            else if (k == 273)  v = ldany(We1, (size_t)256*INNER + n, f32);
        }
        b1[i] = f2bf(v);
    }
    for (int i = g; i < 3*160*72; i += stride) {
        int c = i / (160*72), rem = i % (160*72), n = rem / 72, kc = rem % 72;
        int k = c*64 + kc;
        float v = 0.f;
        if (kc < 64 && k < INNER) v = ldany(We2, (size_t)k*INNER + n, f32);
        b2[i] = f2bf(v);
    }
    for (int i = g; i < 3*144*72; i += stride) {
        int c = i / (144*72), rem = i % (144*72), n = rem / 72, kc = rem % 72;
        int k = c*64 + kc;
        float v = 0.f;
        if (kc < 64 && k < INNER) {
            if (n < 128)      v = ldany(Wv, (size_t)k*HID + n, f32);
            else if (n < 136) v = ldany(Wa, (size_t)k*HEADS + (n-128), f32);
            else if (n == 136) v = ldany(Wc, (size_t)k, f32);
        }
        b3[i] = f2bf(v);
    }
    for (int i = g; i < 2*128*72; i += stride) {      // Wo [2][128][72]
        int c = i / (128*72), rem = i % (128*72), n = rem / 72, kc = rem % 72;
        int k = c*64 + kc;
        float v = (kc < 64 && k < HID) ? ldany(Wo, (size_t)k*HID + n, f32) : 0.f;
        b4[i] = f2bf(v);
    }
    for (int i = g; i < 2*160*72; i += stride) {      // Wn1 [2][160][72]
        int c = i / (160*72), rem = i % (160*72), n = rem / 72, kc = rem % 72;
        int k = c*64 + kc;
        float v = (kc < 64) ? ldany(Wn1, (size_t)k*INNER + n, f32) : 0.f;
        b5[i] = f2bf(v);
    }
    for (int i = g; i < 3*128*72; i += stride) {      // Wn2 [3][128][72]
        int c = i / (128*72), rem = i % (128*72), n = rem / 72, kc = rem % 72;
        int k = c*64 + kc;
        float v = (kc < 64 && k < INNER) ? ldany(Wn2, (size_t)k*HID + n, f32) : 0.f;
        b6[i] = f2bf(v);
    }
    for (int i = g; i < 256*72; i += stride) {        // Wf1 [256][72] (K=64)
        int n = i / 72, kc = i % 72;
        float v = (kc < 64) ? ldany(Wf1, (size_t)kc*256 + n, f32) : 0.f;
        b7[i] = f2bf(v);
    }
    for (int i = g; i < 256*72; i += stride) {        // Wf2 [256][72]
        int n = i / 72, kc = i % 72;
        float v = (kc < 64) ? ldany(Wf2, (size_t)kc*256 + n, f32) : 0.f;
        b8[i] = f2bf(v);
    }
}

// ---------------------------------------------------------------------------
// MFMA edge kernel (unchanged from R4; 503 us, proven correct)
// ---------------------------------------------------------------------------
template<bool F32>
__device__ __forceinline__ void edge_body(
    const void* h, const void* coords, const void* a,
    const int* __restrict__ src, const int* __restrict__ dst,
    const u16* __restrict__ We1Tb, const u16* __restrict__ We2Tb,
    const u16* __restrict__ W3Tb,
    const u16* __restrict__ cbe1, const u16* __restrict__ cbe2,
    float* __restrict__ den, float* __restrict__ hagg, float* __restrict__ cacc,
    u16* sB, u16* sF, u16* sM1, u16* sM2,
    float* sex, float* sdiff, float* srad, int* ssrc, int* sdstl)
{
    const int t   = threadIdx.x;
    const int w   = t >> 6;
    const int l   = t & 63;
    const int col = l & 15;
    const int q   = l >> 4;

    float bias1[10], bias2[10];
    #pragma unroll
    for (int nt = 0; nt < 10; nt++) {
        bias1[nt] = bf2f(cbe1[nt*16 + col]);
        bias2[nt] = bf2f(cbe2[nt*16 + col]);
    }

    for (int tile = blockIdx.x; tile < N_EDGES/64; tile += gridDim.x) {
        const int e0 = tile * 64;
        __syncthreads();
        if (t < 64) {
            int e = e0 + t;
            int s = src[e], d = dst[e];
            ssrc[t] = s; sdstl[t] = d;
            float dx = ldg1<F32>(coords, (size_t)s*3+0) - ldg1<F32>(coords, (size_t)d*3+0);
            float dy = ldg1<F32>(coords, (size_t)s*3+1) - ldg1<F32>(coords, (size_t)d*3+1);
            float dz = ldg1<F32>(coords, (size_t)s*3+2) - ldg1<F32>(coords, (size_t)d*3+2);
            sdiff[t*4+0] = dx; sdiff[t*4+1] = dy; sdiff[t*4+2] = dz;
            float r2 = dx*dx + dy*dy + dz*dz;
            srad[t] = r2;
            sdiff[t*4+3] = 1.0f / (sqrtf(r2 + 1e-5f) + 1.0f);
        }
        __syncthreads();

        f32x4 acc1[10];
        #pragma unroll
        for (int nt = 0; nt < 10; nt++)
            acc1[nt] = (f32x4){bias1[nt], bias1[nt], bias1[nt], bias1[nt]};

        for (int c = 0; c < 5; c++) {
            {
                const uint4* g4 = (const uint4*)(We1Tb + (size_t)c*160*72);
                uint4* s4 = (uint4*)sB;
                for (int i = t; i < 1440; i += 256) s4[i] = g4[i];
            }
            {
                int e = t >> 2, part = t & 3;
                if (c < 4) {
                    int node = (c < 2) ? ssrc[e] : sdstl[e];
                    int c0 = (c & 1) * 64 + part * 16;
                    ld8a<F32>(h, (size_t)node*HID + c0,     &sF[e*72 + part*16]);
                    ld8a<F32>(h, (size_t)node*HID + c0 + 8, &sF[e*72 + part*16 + 8]);
                } else {
                    __align__(16) u16 tmp[16];
                    #pragma unroll
                    for (int j = 0; j < 16; j++) tmp[j] = 0;
                    if (part == 0) {
                        float r2 = srad[e];
                        tmp[0] = f2bf(r2);
                        for (int j = 0; j < 15; j++)
                            tmp[1+j] = f2bf(ldg1<F32>(a, (size_t)(e0+e)*EDGE_F + j));
                    } else if (part == 1) {
                        tmp[0] = f2bf(ldg1<F32>(a, (size_t)(e0+e)*EDGE_F + 15));
                        float r2 = srad[e];
                        tmp[1] = f2bf(r2 - bf2f(f2bf(r2)));
                    }
                    *(uint4*)(&sF[e*72 + part*16])     = ((uint4*)tmp)[0];
                    *(uint4*)(&sF[e*72 + part*16 + 8]) = ((uint4*)tmp)[1];
                }
            }
            __syncthreads();
            const u16* fbase = &sF[(w*16 + col)*72];
            #pragma unroll
            for (int ks = 0; ks < 2; ks++) {
                short8 af = *(const short8*)(fbase + ks*32 + q*8);
                #pragma unroll
                for (int nt = 0; nt < 10; nt++) {
                    short8 bfr = *(const short8*)(&sB[(nt*16 + col)*72 + ks*32 + q*8]);
                    acc1[nt] = __builtin_amdgcn_mfma_f32_16x16x32_bf16(af, bfr, acc1[nt], 0, 0, 0);
                }
            }
            __syncthreads();
        }
        #pragma unroll
        for (int nt = 0; nt < 10; nt++)
            #pragma unroll
            for (int r = 0; r < 4; r++)
                sM1[(w*16 + q*4 + r)*168 + nt*16 + col] = f2bf(silu(acc1[nt][r]));

        f32x4 acc2[10];
        #pragma unroll
        for (int nt = 0; nt < 10; nt++)
            acc2[nt] = (f32x4){bias2[nt], bias2[nt], bias2[nt], bias2[nt]};

        for (int c = 0; c < 3; c++) {
            {
                const uint4* g4 = (const uint4*)(We2Tb + (size_t)c*160*72);
                uint4* s4 = (uint4*)sB;
                for (int i = t; i < 1440; i += 256) s4[i] = g4[i];
            }
            __syncthreads();
            const int nks = (c < 2) ? 2 : 1;
            for (int ks = 0; ks < nks; ks++) {
                short8 af = *(const short8*)(&sM1[(w*16 + col)*168 + c*64 + ks*32 + q*8]);
                #pragma unroll
                for (int nt = 0; nt < 10; nt++) {
                    short8 bfr = *(const short8*)(&sB[(nt*16 + col)*72 + ks*32 + q*8]);
                    acc2[nt] = __builtin_amdgcn_mfma_f32_16x16x32_bf16(af, bfr, acc2[nt], 0, 0, 0);
                }
            }
            __syncthreads();
        }
        #pragma unroll
        for (int nt = 0; nt < 10; nt++)
            #pragma unroll
            for (int r = 0; r < 4; r++)
                sM2[(w*16 + q*4 + r)*168 + nt*16 + col] = f2bf(silu(acc2[nt][r]));

        f32x4 acc3[9];
        #pragma unroll
        for (int nt = 0; nt < 9; nt++) acc3[nt] = (f32x4){0.f, 0.f, 0.f, 0.f};

        for (int c = 0; c < 3; c++) {
            {
                const uint4* g4 = (const uint4*)(W3Tb + (size_t)c*144*72);
                uint4* s4 = (uint4*)sB;
                for (int i = t; i < 1296; i += 256) s4[i] = g4[i];
            }
            __syncthreads();
            const int nks = (c < 2) ? 2 : 1;
            for (int ks = 0; ks < nks; ks++) {
                short8 af = *(const short8*)(&sM2[(w*16 + col)*168 + c*64 + ks*32 + q*8]);
                #pragma unroll
                for (int nt = 0; nt < 9; nt++) {
                    short8 bfr = *(const short8*)(&sB[(nt*16 + col)*72 + ks*32 + q*8]);
                    acc3[nt] = __builtin_amdgcn_mfma_f32_16x16x32_bf16(af, bfr, acc3[nt], 0, 0, 0);
                }
            }
            __syncthreads();
        }

        const int mbase = w*16 + q*4;
        if (col < 8) {
            #pragma unroll
            for (int r = 0; r < 4; r++) {
                int m = mbase + r;
                int d = sdstl[m];
                float ex = __expf(fminf(fmaxf(acc3[8][r], -30.f), 30.f));
                sex[m*8 + col] = ex;
                atomicAdd(&den[(size_t)d*8 + col], ex);
            }
        } else if (col == 8) {
            #pragma unroll
            for (int r = 0; r < 4; r++) {
                int m = mbase + r;
                int d = sdstl[m];
                float lc = fminf(fmaxf(acc3[8][r], -1e6f), 1e6f);
                float invf = sdiff[m*4 + 3];
                #pragma unroll
                for (int j = 0; j < 3; j++)
                    atomicAdd(&cacc[(size_t)d*3 + j], lc * sdiff[m*4 + j] * invf);
            }
        }
        __syncthreads();
        #pragma unroll
        for (int nt = 0; nt < 8; nt++) {
            #pragma unroll
            for (int r = 0; r < 4; r++) {
                int m = mbase + r;
                int d = sdstl[m];
                atomicAdd(&hagg[(size_t)d*HID + nt*16 + col], acc3[nt][r] * sex[m*8 + nt]);
            }
        }
    }
}

__global__ __launch_bounds__(256, 2)
void edge_kernel(const int* __restrict__ flag,
                 const void* h, const void* coords, const void* a,
                 const int* __restrict__ src, const int* __restrict__ dst,
                 const u16* __restrict__ We1Tb, const u16* __restrict__ We2Tb,
                 const u16* __restrict__ W3Tb,
                 const u16* __restrict__ cbe1, const u16* __restrict__ cbe2,
                 float* __restrict__ den, float* __restrict__ hagg,
                 float* __restrict__ cacc)
{
    __shared__ __align__(16) u16 sB[160*72];
    __shared__ __align__(16) u16 sF[64*72];
    __shared__ __align__(16) u16 sM1[64*168];
    __shared__ __align__(16) u16 sM2[64*168];
    __shared__ float sex[64*8];
    __shared__ float sdiff[64*4];
    __shared__ float srad[64];
    __shared__ int   ssrc[64];
    __shared__ int   sdstl[64];
    if (*flag)
        edge_body<true>(h, coords, a, src, dst, We1Tb, We2Tb, W3Tb, cbe1, cbe2,
                        den, hagg, cacc, sB, sF, sM1, sM2, sex, sdiff, srad, ssrc, sdstl);
    else
        edge_body<false>(h, coords, a, src, dst, We1Tb, We2Tb, W3Tb, cbe1, cbe2,
                         den, hagg, cacc, sB, sF, sM1, sM2, sex, sdiff, srad, ssrc, sdstl);
}

// ---------------------------------------------------------------------------
// Fused MFMA node kernel: one 64-node tile per block.
// g=hagg/den -> f2=g@Wo -> film1=y@Wf1 (regs) -> LN1/res1/h1 -> t=silu(h1@Wn1)
// -> f3=t@Wn2 -> film2 -> LN2 -> h2/res2; coords tail.
// ---------------------------------------------------------------------------
template<bool F32>
__device__ __forceinline__ void node_body(
    const void* h, const void* res, const void* coords, const void* y,
    const float* __restrict__ den, const float* __restrict__ hagg,
    const float* __restrict__ cacc,
    const u16* __restrict__ WoB, const u16* __restrict__ Wn1B,
    const u16* __restrict__ Wn2B, const u16* __restrict__ Wf1B,
    const u16* __restrict__ Wf2B,
    const u16* __restrict__ cbn1, const u16* __restrict__ cbn2,
    const u16* __restrict__ cbf1, const u16* __restrict__ cbf2,
    void* out,
    u16* sB, u16* sG, u16* sM, u16* sM2, u16* sR1, u16* sH, u16* sY)
{
    const int t = threadIdx.x;
    const int w = t >> 6, l = t & 63, col = l & 15, q = l >> 4;
    const int n0 = blockIdx.x * 64;

    // -------- stage h, y, g --------
    {
        int node = t >> 2, part = t & 3;
        int gn = n0 + node;
        bool ok = gn < N_NODES;
        uint4 z = {0,0,0,0};
        #pragma unroll
        for (int j = 0; j < 32; j += 8) {
            if (ok) ld8a<F32>(h, (size_t)gn*HID + part*32 + j, &sH[node*136 + part*32 + j]);
            else    *(uint4*)&sH[node*136 + part*32 + j] = z;
        }
        if (ok) {
            ld8a<F32>(y, (size_t)gn*ADY + part*16,     &sY[node*72 + part*16]);
            ld8a<F32>(y, (size_t)gn*ADY + part*16 + 8, &sY[node*72 + part*16 + 8]);
        } else {
            *(uint4*)&sY[node*72 + part*16]     = z;
            *(uint4*)&sY[node*72 + part*16 + 8] = z;
        }
        #pragma unroll
        for (int c = 0; c < 2; c++) {
            float inv = 0.f;
            if (ok) {
                float dd = den[(size_t)gn*8 + c*4 + part];
                inv = dd > 0.f ? 1.f/dd : 0.f;
            }
            __align__(16) u16 tmp[16];
            #pragma unroll
            for (int j = 0; j < 16; j += 4) {
                float4 v = ok ? *(const float4*)(hagg + (size_t)gn*HID + c*64 + part*16 + j)
                              : (float4){0.f,0.f,0.f,0.f};
                tmp[j+0]=f2bf(v.x*inv); tmp[j+1]=f2bf(v.y*inv);
                tmp[j+2]=f2bf(v.z*inv); tmp[j+3]=f2bf(v.w*inv);
            }
            *(uint4*)&sG[c*4608 + node*72 + part*16]     = ((uint4*)tmp)[0];
            *(uint4*)&sG[c*4608 + node*72 + part*16 + 8] = ((uint4*)tmp)[1];
        }
    }

    // -------- Wo GEMM: f2 --------
    f32x4 aF2[8];
    #pragma unroll
    for (int nt = 0; nt < 8; nt++) aF2[nt] = (f32x4){0.f,0.f,0.f,0.f};
    for (int c = 0; c < 2; c++) {
        __syncthreads();
        { const uint4* g4 = (const uint4*)(WoB + (size_t)c*128*72); uint4* s4 = (uint4*)sB;
          for (int i = t; i < 1152; i += 256) s4[i] = g4[i]; }
        __syncthreads();
        #pragma unroll
        for (int ks = 0; ks < 2; ks++) {
            short8 af = *(const short8*)&sG[c*4608 + (w*16+col)*72 + ks*32 + q*8];
            #pragma unroll
            for (int nt = 0; nt < 8; nt++) {
                short8 b = *(const short8*)&sB[(nt*16+col)*72 + ks*32 + q*8];
                aF2[nt] = __builtin_amdgcn_mfma_f32_16x16x32_bf16(af, b, aF2[nt], 0, 0, 0);
            }
        }
    }

    // -------- film1 GEMM (kept in regs) --------
    f32x4 aFl[16];
    #pragma unroll
    for (int nt = 0; nt < 16; nt++) {
        float v = bf2f(cbf1[nt*16 + col]);
        aFl[nt] = (f32x4){v,v,v,v};
    }
    __syncthreads();
    { const uint4* g4 = (const uint4*)Wf1B; uint4* s4 = (uint4*)sB;
      for (int i = t; i < 2304; i += 256) s4[i] = g4[i]; }
    __syncthreads();
    #pragma unroll
    for (int ks = 0; ks < 2; ks++) {
        short8 af = *(const short8*)&sY[(w*16+col)*72 + ks*32 + q*8];
        #pragma unroll
        for (int nt = 0; nt < 16; nt++) {
            short8 b = *(const short8*)&sB[(nt*16+col)*72 + ks*32 + q*8];
            aFl[nt] = __builtin_amdgcn_mfma_f32_16x16x32_bf16(af, b, aFl[nt], 0, 0, 0);
        }
    }

    // -------- LN1 + res1 + h1 --------
    {
        float xv[8][4], s[4], ss[4];
        #pragma unroll
        for (int r = 0; r < 4; r++) { s[r] = 0.f; ss[r] = 0.f; }
        #pragma unroll
        for (int nt = 0; nt < 8; nt++)
            #pragma unroll
            for (int r = 0; r < 4; r++) {
                float x = bf2f(sH[(w*16+q*4+r)*136 + nt*16+col]) + aF2[nt][r];
                xv[nt][r] = x; s[r] += x; ss[r] += x*x;
            }
        #pragma unroll
        for (int r = 0; r < 4; r++)
            for (int off = 1; off <= 8; off <<= 1) {
                s[r]  += __shfl_xor(s[r], off);
                ss[r] += __shfl_xor(ss[r], off);
            }
        float mu[4], rs[4];
        #pragma unroll
        for (int r = 0; r < 4; r++) {
            mu[r] = s[r] * (1.f/128.f);
            float var = ss[r] * (1.f/128.f) - mu[r]*mu[r];
            rs[r] = rsqrtf(fmaxf(var, 0.f) + 1e-5f);
        }
        #pragma unroll
        for (int nt = 0; nt < 8; nt++)
            #pragma unroll
            for (int r = 0; r < 4; r++) {
                int m = w*16+q*4+r, n = nt*16+col, gn = n0+m;
                float h1 = (xv[nt][r]-mu[r])*rs[r]*(1.f+aFl[nt][r]) + aFl[nt+8][r];
                sM[m*168 + n] = f2bf(h1);
                float r1 = aF2[nt][r];
                if (gn < N_NODES) r1 += ldg1<F32>(res, (size_t)gn*HID + n);
                sR1[m*128 + n] = f2bf(r1);
            }
    }

    // -------- n1 GEMM: t = silu(h1@Wn1+bn1) --------
    f32x4 aT[10];
    #pragma unroll
    for (int nt = 0; nt < 10; nt++) {
        float v = bf2f(cbn1[nt*16 + col]);
        aT[nt] = (f32x4){v,v,v,v};
    }
    for (int c = 0; c < 2; c++) {
        __syncthreads();
        { const uint4* g4 = (const uint4*)(Wn1B + (size_t)c*160*72); uint4* s4 = (uint4*)sB;
          for (int i = t; i < 1440; i += 256) s4[i] = g4[i]; }
        __syncthreads();
        #pragma unroll
        for (int ks = 0; ks < 2; ks++) {
            short8 af = *(const short8*)&sM[(w*16+col)*168 + c*64 + ks*32 + q*8];
            #pragma unroll
            for (int nt = 0; nt < 10; nt++) {
                short8 b = *(const short8*)&sB[(nt*16+col)*72 + ks*32 + q*8];
                aT[nt] = __builtin_amdgcn_mfma_f32_16x16x32_bf16(af, b, aT[nt], 0, 0, 0);
            }
        }
    }
    #pragma unroll
    for (int nt = 0; nt < 10; nt++)
        #pragma unroll
        for (int r = 0; r < 4; r++)
            sM2[(w*16+q*4+r)*168 + nt*16+col] = f2bf(silu(aT[nt][r]));

    // -------- n2 GEMM: f3 = t@Wn2+bn2 --------
    f32x4 aF3[8];
    #pragma unroll
    for (int nt = 0; nt < 8; nt++) {
        float v = bf2f(cbn2[nt*16 + col]);
        aF3[nt] = (f32x4){v,v,v,v};
    }
    for (int c = 0; c < 3; c++) {
        __syncthreads();
        { const uint4* g4 = (const uint4*)(Wn2B + (size_t)c*128*72); uint4* s4 = (uint4*)sB;
          for (int i = t; i < 1152; i += 256) s4[i] = g4[i]; }
        __syncthreads();
        const int nks = (c < 2) ? 2 : 1;
        for (int ks = 0; ks < nks; ks++) {
            short8 af = *(const short8*)&sM2[(w*16+col)*168 + c*64 + ks*32 + q*8];
            #pragma unroll
            for (int nt = 0; nt < 8; nt++) {
                short8 b = *(const short8*)&sB[(nt*16+col)*72 + ks*32 + q*8];
                aF3[nt] = __builtin_amdgcn_mfma_f32_16x16x32_bf16(af, b, aF3[nt], 0, 0, 0);
            }
        }
    }

    // -------- film2 GEMM --------
    #pragma unroll
    for (int nt = 0; nt < 16; nt++) {
        float v = bf2f(cbf2[nt*16 + col]);
        aFl[nt] = (f32x4){v,v,v,v};
    }
    __syncthreads();
    { const uint4* g4 = (const uint4*)Wf2B; uint4* s4 = (uint4*)sB;
      for (int i = t; i < 2304; i += 256) s4[i] = g4[i]; }
    __syncthreads();
    #pragma unroll
    for (int ks = 0; ks < 2; ks++) {
        short8 af = *(const short8*)&sY[(w*16+col)*72 + ks*32 + q*8];
        #pragma unroll
        for (int nt = 0; nt < 16; nt++) {
            short8 b = *(const short8*)&sB[(nt*16+col)*72 + ks*32 + q*8];
            aFl[nt] = __builtin_amdgcn_mfma_f32_16x16x32_bf16(af, b, aFl[nt], 0, 0, 0);
        }
    }

    // -------- LN2 + h2/res2 --------
    {
        float xv[8][4], s[4], ss[4];
        #pragma unroll
        for (int r = 0; r < 4; r++) { s[r] = 0.f; ss[r] = 0.f; }
        #pragma unroll
        for (int nt = 0; nt < 8; nt++)
            #pragma unroll
            for (int r = 0; r < 4; r++) {
                float x = bf2f(sM[(w*16+q*4+r)*168 + nt*16+col]) + aF3[nt][r];
                xv[nt][r] = x; s[r] += x; ss[r] += x*x;
            }
        #pragma unroll
        for (int r = 0; r < 4; r++)
            for (int off = 1; off <= 8; off <<= 1) {
                s[r]  += __shfl_xor(s[r], off);
                ss[r] += __shfl_xor(ss[r], off);
            }
        float mu[4], rs[4];
        #pragma unroll
        for (int r = 0; r < 4; r++) {
            mu[r] = s[r] * (1.f/128.f);
            float var = ss[r] * (1.f/128.f) - mu[r]*mu[r];
            rs[r] = rsqrtf(fmaxf(var, 0.f) + 1e-5f);
        }
        #pragma unroll
        for (int nt = 0; nt < 8; nt++)
            #pragma unroll
            for (int r = 0; r < 4; r++) {
                int m = w*16+q*4+r, n = nt*16+col, gn = n0+m;
                if (gn < N_NODES) {
                    float h2 = (xv[nt][r]-mu[r])*rs[r]*(1.f+aFl[nt][r]) + aFl[nt+8][r];
                    stg1<F32>(out, (size_t)gn*HID + n, h2);
                    stg1<F32>(out, (size_t)OUT_RES + (size_t)gn*HID + n,
                              bf2f(sR1[m*128 + n]) + aF3[nt][r]);
                }
            }
    }

    // -------- coords --------
    if (t < 64) {
        int gn = n0 + t;
        if (gn < N_NODES) {
            #pragma unroll
            for (int j = 0; j < 3; j++)
                stg1<F32>(out, (size_t)OUT_CRD + (size_t)gn*3 + j,
                          ldg1<F32>(coords, (size_t)gn*3 + j) + cacc[(size_t)gn*3 + j]);
        }
    }
}

__global__ __launch_bounds__(256, 1)
void node_kernel(const int* __restrict__ flag,
                 const void* h, const void* res, const void* coords, const void* y,
                 const float* __restrict__ den, const float* __restrict__ hagg,
                 const float* __restrict__ cacc,
                 const u16* __restrict__ WoB, const u16* __restrict__ Wn1B,
                 const u16* __restrict__ Wn2B, const u16* __restrict__ Wf1B,
                 const u16* __restrict__ Wf2B,
                 const u16* __restrict__ cbn1, const u16* __restrict__ cbn2,
                 const u16* __restrict__ cbf1, const u16* __restrict__ cbf2,
                 void* out)
{
    __shared__ __align__(16) u16 sB[256*72];    // 36864
    __shared__ __align__(16) u16 sG[2*64*72];   // 18432
    __shared__ __align__(16) u16 sM[64*168];    // 21504
    __shared__ __align__(16) u16 sM2[64*168];   // 21504
    __shared__ __align__(16) u16 sR1[64*128];   // 16384
    __shared__ __align__(16) u16 sH[64*136];    // 17408
    __shared__ __align__(16) u16 sY[64*72];     //  9216
    if (*flag)
        node_body<true>(h, res, coords, y, den, hagg, cacc, WoB, Wn1B, Wn2B,
                        Wf1B, Wf2B, cbn1, cbn2, cbf1, cbf2, out,
                        sB, sG, sM, sM2, sR1, sH, sY);
    else
        node_body<false>(h, res, coords, y, den, hagg, cacc, WoB, Wn1B, Wn2B,
                         Wf1B, Wf2B, cbn1, cbn2, cbf1, cbf2, out,
                         sB, sG, sM, sM2, sR1, sH, sY);
}

// ---------------------------------------------------------------------------
extern "C" void kernel_launch(void* const* d_in, const int* in_sizes, int n_in,
                              void* d_out, int out_size, void* d_ws, size_t ws_size,
                              hipStream_t stream)
{
    const void* h      = d_in[0];
    const void* coords = d_in[1];
    const void* a      = d_in[2];
    const void* y      = d_in[3];
    const void* res    = d_in[4];
    const int* src     = (const int*)d_in[5];
    const int* dst     = (const int*)d_in[6];

    char* ws = (char*)d_ws;
    int*   flag = (int*)(ws + FLAG_OFF);
    float* den  = (float*)(ws + DEN_OFF);
    float* cacc = (float*)(ws + CACC_OFF);
    float* hagg = (float*)(ws + HAGG_OFF);

    const int wn[16]  = {43680, 25600, 20480, 1280, 160, 160, 160, 16384,
                         20480, 160, 20480, 128, 16384, 256, 16384, 256};
    const int widx[16] = {7, 9, 12, 13, 11, 8, 10, 14, 15, 16, 17, 18, 19, 20, 21, 22};
    u64 off = CW_BASE;
    CvtArgs args;
    u64 offs[16];
    for (int i = 0; i < 16; i++) {
        args.src[i] = d_in[widx[i]];
        args.dstoff[i] = off;
        args.n[i] = wn[i];
        offs[i] = off;
        off += (u64)wn[i] * 2;
    }
    u64 bw1 = (off + 255) & ~(u64)255;
    u64 bw2 = bw1 + (u64)5*160*72*2;
    u64 bw3 = bw2 + (u64)3*160*72*2;
    u64 bw4 = bw3 + (u64)3*144*72*2;
    u64 bw5 = bw4 + (u64)2*128*72*2;
    u64 bw6 = bw5 + (u64)2*160*72*2;
    u64 bw7 = bw6 + (u64)3*128*72*2;
    u64 bw8 = bw7 + (u64)256*72*2;

    const u16* cbe1 = (const u16*)(ws + offs[5]);
    const u16* cbe2 = (const u16*)(ws + offs[6]);
    const u16* cbn1 = (const u16*)(ws + offs[9]);
    const u16* cbn2 = (const u16*)(ws + offs[11]);
    const u16* cbf1 = (const u16*)(ws + offs[13]);
    const u16* cbf2 = (const u16*)(ws + offs[15]);
    const u16* We1Tb = (const u16*)(ws + bw1);
    const u16* We2Tb = (const u16*)(ws + bw2);
    const u16* W3Tb  = (const u16*)(ws + bw3);
    const u16* WoB   = (const u16*)(ws + bw4);
    const u16* Wn1B  = (const u16*)(ws + bw5);
    const u16* Wn2B  = (const u16*)(ws + bw6);
    const u16* Wf1B  = (const u16*)(ws + bw7);
    const u16* Wf2B  = (const u16*)(ws + bw8);

    hipMemsetAsync(d_ws, 0, MEMSET_BYTES, stream);

    detect_kernel<<<1, 256, 0, stream>>>(h, flag);
    cvt_kernel<<<dim3(8, 16), 256, 0, stream>>>(flag, ws, args);
    blockw_kernel<<<64, 256, 0, stream>>>(flag, ws, bw1, bw2, bw3, bw4,
                                          bw5, bw6, bw7, bw8,
                                          d_in[7], d_in[9], d_in[12], d_in[13], d_in[11],
                                          d_in[14], d_in[15], d_in[17], d_in[19], d_in[21]);

    edge_kernel<<<512, 256, 0, stream>>>(flag, h, coords, a, src, dst,
                                         We1Tb, We2Tb, W3Tb, cbe1, cbe2,
                                         den, hagg, cacc);

    node_kernel<<<(N_NODES + 63)/64, 256, 0, stream>>>(
        flag, h, res, coords, y, den, hagg, cacc,
        WoB, Wn1B, Wn2B, Wf1B, Wf2B, cbn1, cbn2, cbf1, cbf2, d_out);
}

// Round 6
// 574.646 us; speedup vs baseline: 5.2635x; 1.3139x over previous
//
#include <hip/hip_runtime.h>
#include <math.h>

#define N_NODES 25000
#define N_EDGES 400000
#define HID 128
#define EDGE_F 16
#define ADY 64
#define INNER 160
#define MSG_F 273
#define HEADS 8

// element offsets inside d_out (h2 | coords | res2)
#define OUT_CRD (N_NODES * HID)
#define OUT_RES (N_NODES * (HID + 3))

// ws byte offsets (16-aligned)
#define FLAG_OFF 0
#define DEN_OFF  256
#define CACC_OFF 800256
#define HAGG_OFF 1100288
#define CW_BASE  13900288            // canonical bf16 flat weights
#define MEMSET_BYTES 13900288

typedef unsigned short u16;
typedef unsigned int u32;
typedef unsigned long long u64;
typedef __attribute__((ext_vector_type(8))) short short8;
typedef __attribute__((ext_vector_type(4))) float f32x4;

__device__ __forceinline__ float bf2f(u16 v) {
    union { u32 u; float f; } x; x.u = ((u32)v) << 16; return x.f;
}
__device__ __forceinline__ u16 f2bf(float f) {
    union { float ff; u32 u; } x; x.ff = f;
    u32 u = x.u;
    u32 rounding = 0x7FFFu + ((u >> 16) & 1u);
    u += rounding;
    return (u16)(u >> 16);
}
__device__ __forceinline__ float silu(float z) {
    z = fminf(fmaxf(z, -30000.f), 30000.f);
    return z / (1.0f + __expf(-z));
}

template<bool F32> __device__ __forceinline__ float ldg1(const void* p, size_t i) {
    if (F32) return ((const float*)p)[i];
    return bf2f(((const u16*)p)[i]);
}
template<bool F32> __device__ __forceinline__ void stg1(void* p, size_t i, float v) {
    if (F32) ((float*)p)[i] = v;
    else     ((u16*)p)[i] = f2bf(v);
}
template<bool F32> __device__ __forceinline__ void ld8a(const void* p, size_t i, u16* dst) {
    if (F32) {
        const float* fp = (const float*)p + i;
        float4 v0 = ((const float4*)fp)[0];
        float4 v1 = ((const float4*)fp)[1];
        __align__(16) u16 tmp[8] = { f2bf(v0.x), f2bf(v0.y), f2bf(v0.z), f2bf(v0.w),
                                     f2bf(v1.x), f2bf(v1.y), f2bf(v1.z), f2bf(v1.w) };
        *(uint4*)dst = *(const uint4*)tmp;
    } else {
        *(uint4*)dst = *(const uint4*)((const u16*)p + i);
    }
}
__device__ __forceinline__ float ldany(const void* p, size_t i, bool f32) {
    return f32 ? ((const float*)p)[i] : bf2f(((const u16*)p)[i]);
}

// ---------------------------------------------------------------------------
// dtype detector (flag=1 -> fp32 inputs)
// ---------------------------------------------------------------------------
__global__ void detect_kernel(const void* h, int* flag) {
    __shared__ float red[256];
    const int t = threadIdx.x;
    const u16* p = (const u16*)h;
    float mx = 0.f;
    for (int i = 0; i < 8; i++) {
        int idx = (t * 8 + i) * 97;
        float v = fabsf(bf2f(p[idx * 2]));
        mx = fmaxf(mx, v);
    }
    red[t] = mx;
    __syncthreads();
    for (int s = 128; s > 0; s >>= 1) {
        if (t < s) red[t] = fmaxf(red[t], red[t + s]);
        __syncthreads();
    }
    if (t == 0) flag[0] = (red[0] > 1e10f || red[0] == 0.f) ? 1 : 0;
}

// ---------------------------------------------------------------------------
// flat weight canonicalization: 16 tensors -> bf16 copies in ws
// ---------------------------------------------------------------------------
struct CvtArgs {
    const void* src[16];
    u64 dstoff[16];
    int n[16];
};
__global__ void cvt_kernel(const int* __restrict__ flag, char* wsbase, CvtArgs args) {
    const int ten = blockIdx.y;
    const void* s = args.src[ten];
    u16* d = (u16*)(wsbase + args.dstoff[ten]);
    const int n = args.n[ten];
    const bool f32 = (*flag != 0);
    if (f32) {
        const float* sf = (const float*)s;
        for (int i = blockIdx.x * 256 + threadIdx.x; i < n; i += gridDim.x * 256)
            d[i] = f2bf(sf[i]);
    } else {
        const u16* su = (const u16*)s;
        for (int i = blockIdx.x * 256 + threadIdx.x; i < n; i += gridDim.x * 256)
            d[i] = su[i];
    }
}

// ---------------------------------------------------------------------------
// blocked/transposed [n][72] weight builder for all MFMA GEMMs
// ---------------------------------------------------------------------------
__global__ void blockw_kernel(const int* __restrict__ flag, char* ws,
                              u64 b1off, u64 b2off, u64 b3off, u64 b4off,
                              u64 b5off, u64 b6off, u64 b7off, u64 b8off,
                              const void* We1, const void* We2,
                              const void* Wv, const void* Wa, const void* Wc,
                              const void* Wo, const void* Wn1, const void* Wn2,
                              const void* Wf1, const void* Wf2)
{
    const bool f32 = (*flag != 0);
    u16* b1 = (u16*)(ws + b1off);
    u16* b2 = (u16*)(ws + b2off);
    u16* b3 = (u16*)(ws + b3off);
    u16* b4 = (u16*)(ws + b4off);
    u16* b5 = (u16*)(ws + b5off);
    u16* b6 = (u16*)(ws + b6off);
    u16* b7 = (u16*)(ws + b7off);
    u16* b8 = (u16*)(ws + b8off);
    const int g = blockIdx.x * 256 + threadIdx.x;
    const int stride = gridDim.x * 256;
    for (int i = g; i < 5*160*72; i += stride) {
        int c = i / (160*72), rem = i % (160*72), n = rem / 72, kc = rem % 72;
        int k = c*64 + kc;
        float v = 0.f;
        if (kc < 64) {
            if (k < MSG_F)      v = ldany(We1, (size_t)k*INNER + n, f32);
            else if (k == 273)  v = ldany(We1, (size_t)256*INNER + n, f32);
        }
        b1[i] = f2bf(v);
    }
    for (int i = g; i < 3*160*72; i += stride) {
        int c = i / (160*72), rem = i % (160*72), n = rem / 72, kc = rem % 72;
        int k = c*64 + kc;
        float v = 0.f;
        if (kc < 64 && k < INNER) v = ldany(We2, (size_t)k*INNER + n, f32);
        b2[i] = f2bf(v);
    }
    for (int i = g; i < 3*144*72; i += stride) {
        int c = i / (144*72), rem = i % (144*72), n = rem / 72, kc = rem % 72;
        int k = c*64 + kc;
        float v = 0.f;
        if (kc < 64 && k < INNER) {
            if (n < 128)      v = ldany(Wv, (size_t)k*HID + n, f32);
            else if (n < 136) v = ldany(Wa, (size_t)k*HEADS + (n-128), f32);
            else if (n == 136) v = ldany(Wc, (size_t)k, f32);
        }
        b3[i] = f2bf(v);
    }
    for (int i = g; i < 2*128*72; i += stride) {      // Wo [2][128][72]
        int c = i / (128*72), rem = i % (128*72), n = rem / 72, kc = rem % 72;
        int k = c*64 + kc;
        float v = (kc < 64 && k < HID) ? ldany(Wo, (size_t)k*HID + n, f32) : 0.f;
        b4[i] = f2bf(v);
    }
    for (int i = g; i < 2*160*72; i += stride) {      // Wn1 [2][160][72]
        int c = i / (160*72), rem = i % (160*72), n = rem / 72, kc = rem % 72;
        int k = c*64 + kc;
        float v = (kc < 64) ? ldany(Wn1, (size_t)k*INNER + n, f32) : 0.f;
        b5[i] = f2bf(v);
    }
    for (int i = g; i < 3*128*72; i += stride) {      // Wn2 [3][128][72]
        int c = i / (128*72), rem = i % (128*72), n = rem / 72, kc = rem % 72;
        int k = c*64 + kc;
        float v = (kc < 64 && k < INNER) ? ldany(Wn2, (size_t)k*HID + n, f32) : 0.f;
        b6[i] = f2bf(v);
    }
    for (int i = g; i < 256*72; i += stride) {        // Wf1 [256][72] (K=64)
        int n = i / 72, kc = i % 72;
        float v = (kc < 64) ? ldany(Wf1, (size_t)kc*256 + n, f32) : 0.f;
        b7[i] = f2bf(v);
    }
    for (int i = g; i < 256*72; i += stride) {        // Wf2 [256][72]
        int n = i / 72, kc = i % 72;
        float v = (kc < 64) ? ldany(Wf2, (size_t)kc*256 + n, f32) : 0.f;
        b8[i] = f2bf(v);
    }
}

// ---------------------------------------------------------------------------
// MFMA edge kernel v2: one 64-edge tile per block. B-fragments read directly
// from global (L1-cached, shared across waves); LDS only for f / m1 / m2
// (aliased pool, 6 barriers per tile instead of ~24).
// ---------------------------------------------------------------------------
template<bool F32>
__device__ __forceinline__ void edge_body(
    const void* h, const void* coords, const void* a,
    const int* __restrict__ src, const int* __restrict__ dst,
    const u16* __restrict__ We1Tb, const u16* __restrict__ We2Tb,
    const u16* __restrict__ W3Tb,
    const u16* __restrict__ cbe1, const u16* __restrict__ cbe2,
    float* __restrict__ den, float* __restrict__ hagg, float* __restrict__ cacc,
    u16* sPool, float* sex, float* sdiff, float* srad, int* ssrc, int* sdstl)
{
    const int t   = threadIdx.x;
    const int w   = t >> 6;
    const int l   = t & 63;
    const int col = l & 15;
    const int q   = l >> 4;

    u16* sF  = sPool;               // [64][360]  (f, all 5 chunks)
    u16* sM1 = sPool;               // [64][168]  (aliases sF after barrier)
    u16* sM2 = sPool + 64*168;      // [64][168]

    const int e0 = blockIdx.x * 64;

    if (t < 64) {
        int e = e0 + t;
        int s = src[e], d = dst[e];
        ssrc[t] = s; sdstl[t] = d;
        float dx = ldg1<F32>(coords, (size_t)s*3+0) - ldg1<F32>(coords, (size_t)d*3+0);
        float dy = ldg1<F32>(coords, (size_t)s*3+1) - ldg1<F32>(coords, (size_t)d*3+1);
        float dz = ldg1<F32>(coords, (size_t)s*3+2) - ldg1<F32>(coords, (size_t)d*3+2);
        sdiff[t*4+0] = dx; sdiff[t*4+1] = dy; sdiff[t*4+2] = dz;
        float r2 = dx*dx + dy*dy + dz*dz;
        srad[t] = r2;
        sdiff[t*4+3] = 1.0f / (sqrtf(r2 + 1e-5f) + 1.0f);
    }
    __syncthreads();                                    // B1

    // ---- stage ALL f chunks: sF[e][c*72 + kc] ----
    {
        int e = t >> 2, part = t & 3;
        int node_s = ssrc[e], node_d = sdstl[e];
        #pragma unroll
        for (int c = 0; c < 4; c++) {
            int node = (c < 2) ? node_s : node_d;
            int c0 = (c & 1) * 64 + part * 16;
            ld8a<F32>(h, (size_t)node*HID + c0,     &sF[e*360 + c*72 + part*16]);
            ld8a<F32>(h, (size_t)node*HID + c0 + 8, &sF[e*360 + c*72 + part*16 + 8]);
        }
        __align__(16) u16 tmp[16];
        #pragma unroll
        for (int j = 0; j < 16; j++) tmp[j] = 0;
        if (part == 0) {
            float r2 = srad[e];
            tmp[0] = f2bf(r2);                           // kc0 = radial hi
            for (int j = 0; j < 15; j++)
                tmp[1+j] = f2bf(ldg1<F32>(a, (size_t)(e0+e)*EDGE_F + j));
        } else if (part == 1) {
            tmp[0] = f2bf(ldg1<F32>(a, (size_t)(e0+e)*EDGE_F + 15));
            float r2 = srad[e];
            tmp[1] = f2bf(r2 - bf2f(f2bf(r2)));          // kc17 = radial lo
        }
        *(uint4*)(&sF[e*360 + 4*72 + part*16])     = ((uint4*)tmp)[0];
        *(uint4*)(&sF[e*360 + 4*72 + part*16 + 8]) = ((uint4*)tmp)[1];
    }
    __syncthreads();                                    // B2

    // ---- GEMM1: K=320, B from global ----
    f32x4 acc1[10];
    #pragma unroll
    for (int nt = 0; nt < 10; nt++) {
        float v = bf2f(cbe1[nt*16 + col]);
        acc1[nt] = (f32x4){v, v, v, v};
    }
    const u16* fbase = &sF[(w*16 + col)*360];
    #pragma unroll
    for (int c = 0; c < 5; c++) {
        #pragma unroll
        for (int ks = 0; ks < 2; ks++) {
            short8 af = *(const short8*)(fbase + c*72 + ks*32 + q*8);
            const u16* B1 = We1Tb + (size_t)c*160*72 + ks*32 + q*8;
            #pragma unroll
            for (int nt = 0; nt < 10; nt++) {
                short8 b = *(const short8*)(B1 + (nt*16 + col)*72);
                acc1[nt] = __builtin_amdgcn_mfma_f32_16x16x32_bf16(af, b, acc1[nt], 0, 0, 0);
            }
        }
    }
    __syncthreads();                                    // B3 (sF dead)
    #pragma unroll
    for (int nt = 0; nt < 10; nt++)
        #pragma unroll
        for (int r = 0; r < 4; r++)
            sM1[(w*16 + q*4 + r)*168 + nt*16 + col] = f2bf(silu(acc1[nt][r]));
    __syncthreads();                                    // B4

    // ---- GEMM2: K=160 ----
    f32x4 acc2[10];
    #pragma unroll
    for (int nt = 0; nt < 10; nt++) {
        float v = bf2f(cbe2[nt*16 + col]);
        acc2[nt] = (f32x4){v, v, v, v};
    }
    const u16* m1base = &sM1[(w*16 + col)*168];
    #pragma unroll
    for (int k5 = 0; k5 < 5; k5++) {
        short8 af = *(const short8*)(m1base + k5*32 + q*8);
        const u16* B2 = We2Tb + (size_t)(k5>>1)*160*72 + (k5&1)*32 + q*8;
        #pragma unroll
        for (int nt = 0; nt < 10; nt++) {
            short8 b = *(const short8*)(B2 + (nt*16 + col)*72);
            acc2[nt] = __builtin_amdgcn_mfma_f32_16x16x32_bf16(af, b, acc2[nt], 0, 0, 0);
        }
    }
    // sM2 region disjoint from sM1 reads -> no barrier before writes
    #pragma unroll
    for (int nt = 0; nt < 10; nt++)
        #pragma unroll
        for (int r = 0; r < 4; r++)
            sM2[(w*16 + q*4 + r)*168 + nt*16 + col] = f2bf(silu(acc2[nt][r]));
    __syncthreads();                                    // B5

    // ---- GEMM3: N=144, K=160 ----
    f32x4 acc3[9];
    #pragma unroll
    for (int nt = 0; nt < 9; nt++) acc3[nt] = (f32x4){0.f, 0.f, 0.f, 0.f};
    const u16* m2base = &sM2[(w*16 + col)*168];
    #pragma unroll
    for (int k5 = 0; k5 < 5; k5++) {
        short8 af = *(const short8*)(m2base + k5*32 + q*8);
        const u16* B3 = W3Tb + (size_t)(k5>>1)*144*72 + (k5&1)*32 + q*8;
        #pragma unroll
        for (int nt = 0; nt < 9; nt++) {
            short8 b = *(const short8*)(B3 + (nt*16 + col)*72);
            acc3[nt] = __builtin_amdgcn_mfma_f32_16x16x32_bf16(af, b, acc3[nt], 0, 0, 0);
        }
    }

    // ---- epilogue: heads + atomics ----
    const int mbase = w*16 + q*4;
    if (col < 8) {
        #pragma unroll
        for (int r = 0; r < 4; r++) {
            int m = mbase + r;
            int d = sdstl[m];
            float ex = __expf(fminf(fmaxf(acc3[8][r], -30.f), 30.f));
            sex[m*8 + col] = ex;
            atomicAdd(&den[(size_t)d*8 + col], ex);
        }
    } else if (col == 8) {
        #pragma unroll
        for (int r = 0; r < 4; r++) {
            int m = mbase + r;
            int d = sdstl[m];
            float lc = fminf(fmaxf(acc3[8][r], -1e6f), 1e6f);
            float invf = sdiff[m*4 + 3];
            #pragma unroll
            for (int j = 0; j < 3; j++)
                atomicAdd(&cacc[(size_t)d*3 + j], lc * sdiff[m*4 + j] * invf);
        }
    }
    __syncthreads();                                    // B6 (sex visible)
    #pragma unroll
    for (int nt = 0; nt < 8; nt++) {
        #pragma unroll
        for (int r = 0; r < 4; r++) {
            int m = mbase + r;
            int d = sdstl[m];
            atomicAdd(&hagg[(size_t)d*HID + nt*16 + col], acc3[nt][r] * sex[m*8 + nt]);
        }
    }
}

__global__ __launch_bounds__(256, 3)
void edge_kernel(const int* __restrict__ flag,
                 const void* h, const void* coords, const void* a,
                 const int* __restrict__ src, const int* __restrict__ dst,
                 const u16* __restrict__ We1Tb, const u16* __restrict__ We2Tb,
                 const u16* __restrict__ W3Tb,
                 const u16* __restrict__ cbe1, const u16* __restrict__ cbe2,
                 float* __restrict__ den, float* __restrict__ hagg,
                 float* __restrict__ cacc)
{
    __shared__ __align__(16) u16 sPool[64*360];   // 46080 B (f / m1+m2 aliased)
    __shared__ float sex[64*8];
    __shared__ float sdiff[64*4];
    __shared__ float srad[64];
    __shared__ int   ssrc[64];
    __shared__ int   sdstl[64];
    if (*flag)
        edge_body<true>(h, coords, a, src, dst, We1Tb, We2Tb, W3Tb, cbe1, cbe2,
                        den, hagg, cacc, sPool, sex, sdiff, srad, ssrc, sdstl);
    else
        edge_body<false>(h, coords, a, src, dst, We1Tb, We2Tb, W3Tb, cbe1, cbe2,
                         den, hagg, cacc, sPool, sex, sdiff, srad, ssrc, sdstl);
}

// ---------------------------------------------------------------------------
// Fused MFMA node kernel (unchanged from R5)
// ---------------------------------------------------------------------------
template<bool F32>
__device__ __forceinline__ void node_body(
    const void* h, const void* res, const void* coords, const void* y,
    const float* __restrict__ den, const float* __restrict__ hagg,
    const float* __restrict__ cacc,
    const u16* __restrict__ WoB, const u16* __restrict__ Wn1B,
    const u16* __restrict__ Wn2B, const u16* __restrict__ Wf1B,
    const u16* __restrict__ Wf2B,
    const u16* __restrict__ cbn1, const u16* __restrict__ cbn2,
    const u16* __restrict__ cbf1, const u16* __restrict__ cbf2,
    void* out,
    u16* sB, u16* sG, u16* sM, u16* sM2, u16* sR1, u16* sH, u16* sY)
{
    const int t = threadIdx.x;
    const int w = t >> 6, l = t & 63, col = l & 15, q = l >> 4;
    const int n0 = blockIdx.x * 64;

    {
        int node = t >> 2, part = t & 3;
        int gn = n0 + node;
        bool ok = gn < N_NODES;
        uint4 z = {0,0,0,0};
        #pragma unroll
        for (int j = 0; j < 32; j += 8) {
            if (ok) ld8a<F32>(h, (size_t)gn*HID + part*32 + j, &sH[node*136 + part*32 + j]);
            else    *(uint4*)&sH[node*136 + part*32 + j] = z;
        }
        if (ok) {
            ld8a<F32>(y, (size_t)gn*ADY + part*16,     &sY[node*72 + part*16]);
            ld8a<F32>(y, (size_t)gn*ADY + part*16 + 8, &sY[node*72 + part*16 + 8]);
        } else {
            *(uint4*)&sY[node*72 + part*16]     = z;
            *(uint4*)&sY[node*72 + part*16 + 8] = z;
        }
        #pragma unroll
        for (int c = 0; c < 2; c++) {
            float inv = 0.f;
            if (ok) {
                float dd = den[(size_t)gn*8 + c*4 + part];
                inv = dd > 0.f ? 1.f/dd : 0.f;
            }
            __align__(16) u16 tmp[16];
            #pragma unroll
            for (int j = 0; j < 16; j += 4) {
                float4 v = ok ? *(const float4*)(hagg + (size_t)gn*HID + c*64 + part*16 + j)
                              : (float4){0.f,0.f,0.f,0.f};
                tmp[j+0]=f2bf(v.x*inv); tmp[j+1]=f2bf(v.y*inv);
                tmp[j+2]=f2bf(v.z*inv); tmp[j+3]=f2bf(v.w*inv);
            }
            *(uint4*)&sG[c*4608 + node*72 + part*16]     = ((uint4*)tmp)[0];
            *(uint4*)&sG[c*4608 + node*72 + part*16 + 8] = ((uint4*)tmp)[1];
        }
    }

    f32x4 aF2[8];
    #pragma unroll
    for (int nt = 0; nt < 8; nt++) aF2[nt] = (f32x4){0.f,0.f,0.f,0.f};
    for (int c = 0; c < 2; c++) {
        __syncthreads();
        { const uint4* g4 = (const uint4*)(WoB + (size_t)c*128*72); uint4* s4 = (uint4*)sB;
          for (int i = t; i < 1152; i += 256) s4[i] = g4[i]; }
        __syncthreads();
        #pragma unroll
        for (int ks = 0; ks < 2; ks++) {
            short8 af = *(const short8*)&sG[c*4608 + (w*16+col)*72 + ks*32 + q*8];
            #pragma unroll
            for (int nt = 0; nt < 8; nt++) {
                short8 b = *(const short8*)&sB[(nt*16+col)*72 + ks*32 + q*8];
                aF2[nt] = __builtin_amdgcn_mfma_f32_16x16x32_bf16(af, b, aF2[nt], 0, 0, 0);
            }
        }
    }

    f32x4 aFl[16];
    #pragma unroll
    for (int nt = 0; nt < 16; nt++) {
        float v = bf2f(cbf1[nt*16 + col]);
        aFl[nt] = (f32x4){v,v,v,v};
    }
    __syncthreads();
    { const uint4* g4 = (const uint4*)Wf1B; uint4* s4 = (uint4*)sB;
      for (int i = t; i < 2304; i += 256) s4[i] = g4[i]; }
    __syncthreads();
    #pragma unroll
    for (int ks = 0; ks < 2; ks++) {
        short8 af = *(const short8*)&sY[(w*16+col)*72 + ks*32 + q*8];
        #pragma unroll
        for (int nt = 0; nt < 16; nt++) {
            short8 b = *(const short8*)&sB[(nt*16+col)*72 + ks*32 + q*8];
            aFl[nt] = __builtin_amdgcn_mfma_f32_16x16x32_bf16(af, b, aFl[nt], 0, 0, 0);
        }
    }

    {
        float xv[8][4], s[4], ss[4];
        #pragma unroll
        for (int r = 0; r < 4; r++) { s[r] = 0.f; ss[r] = 0.f; }
        #pragma unroll
        for (int nt = 0; nt < 8; nt++)
            #pragma unroll
            for (int r = 0; r < 4; r++) {
                float x = bf2f(sH[(w*16+q*4+r)*136 + nt*16+col]) + aF2[nt][r];
                xv[nt][r] = x; s[r] += x; ss[r] += x*x;
            }
        #pragma unroll
        for (int r = 0; r < 4; r++)
            for (int off = 1; off <= 8; off <<= 1) {
                s[r]  += __shfl_xor(s[r], off);
                ss[r] += __shfl_xor(ss[r], off);
            }
        float mu[4], rs[4];
        #pragma unroll
        for (int r = 0; r < 4; r++) {
            mu[r] = s[r] * (1.f/128.f);
            float var = ss[r] * (1.f/128.f) - mu[r]*mu[r];
            rs[r] = rsqrtf(fmaxf(var, 0.f) + 1e-5f);
        }
        #pragma unroll
        for (int nt = 0; nt < 8; nt++)
            #pragma unroll
            for (int r = 0; r < 4; r++) {
                int m = w*16+q*4+r, n = nt*16+col, gn = n0+m;
                float h1 = (xv[nt][r]-mu[r])*rs[r]*(1.f+aFl[nt][r]) + aFl[nt+8][r];
                sM[m*168 + n] = f2bf(h1);
                float r1 = aF2[nt][r];
                if (gn < N_NODES) r1 += ldg1<F32>(res, (size_t)gn*HID + n);
                sR1[m*128 + n] = f2bf(r1);
            }
    }

    f32x4 aT[10];
    #pragma unroll
    for (int nt = 0; nt < 10; nt++) {
        float v = bf2f(cbn1[nt*16 + col]);
        aT[nt] = (f32x4){v,v,v,v};
    }
    for (int c = 0; c < 2; c++) {
        __syncthreads();
        { const uint4* g4 = (const uint4*)(Wn1B + (size_t)c*160*72); uint4* s4 = (uint4*)sB;
          for (int i = t; i < 1440; i += 256) s4[i] = g4[i]; }
        __syncthreads();
        #pragma unroll
        for (int ks = 0; ks < 2; ks++) {
            short8 af = *(const short8*)&sM[(w*16+col)*168 + c*64 + ks*32 + q*8];
            #pragma unroll
            for (int nt = 0; nt < 10; nt++) {
                short8 b = *(const short8*)&sB[(nt*16+col)*72 + ks*32 + q*8];
                aT[nt] = __builtin_amdgcn_mfma_f32_16x16x32_bf16(af, b, aT[nt], 0, 0, 0);
            }
        }
    }
    #pragma unroll
    for (int nt = 0; nt < 10; nt++)
        #pragma unroll
        for (int r = 0; r < 4; r++)
            sM2[(w*16+q*4+r)*168 + nt*16+col] = f2bf(silu(aT[nt][r]));

    f32x4 aF3[8];
    #pragma unroll
    for (int nt = 0; nt < 8; nt++) {
        float v = bf2f(cbn2[nt*16 + col]);
        aF3[nt] = (f32x4){v,v,v,v};
    }
    for (int c = 0; c < 3; c++) {
        __syncthreads();
        { const uint4* g4 = (const uint4*)(Wn2B + (size_t)c*128*72); uint4* s4 = (uint4*)sB;
          for (int i = t; i < 1152; i += 256) s4[i] = g4[i]; }
        __syncthreads();
        const int nks = (c < 2) ? 2 : 1;
        for (int ks = 0; ks < nks; ks++) {
            short8 af = *(const short8*)&sM2[(w*16+col)*168 + c*64 + ks*32 + q*8];
            #pragma unroll
            for (int nt = 0; nt < 8; nt++) {
                short8 b = *(const short8*)&sB[(nt*16+col)*72 + ks*32 + q*8];
                aF3[nt] = __builtin_amdgcn_mfma_f32_16x16x32_bf16(af, b, aF3[nt], 0, 0, 0);
            }
        }
    }

    #pragma unroll
    for (int nt = 0; nt < 16; nt++) {
        float v = bf2f(cbf2[nt*16 + col]);
        aFl[nt] = (f32x4){v,v,v,v};
    }
    __syncthreads();
    { const uint4* g4 = (const uint4*)Wf2B; uint4* s4 = (uint4*)sB;
      for (int i = t; i < 2304; i += 256) s4[i] = g4[i]; }
    __syncthreads();
    #pragma unroll
    for (int ks = 0; ks < 2; ks++) {
        short8 af = *(const short8*)&sY[(w*16+col)*72 + ks*32 + q*8];
        #pragma unroll
        for (int nt = 0; nt < 16; nt++) {
            short8 b = *(const short8*)&sB[(nt*16+col)*72 + ks*32 + q*8];
            aFl[nt] = __builtin_amdgcn_mfma_f32_16x16x32_bf16(af, b, aFl[nt], 0, 0, 0);
        }
    }

    {
        float xv[8][4], s[4], ss[4];
        #pragma unroll
        for (int r = 0; r < 4; r++) { s[r] = 0.f; ss[r] = 0.f; }
        #pragma unroll
        for (int nt = 0; nt < 8; nt++)
            #pragma unroll
            for (int r = 0; r < 4; r++) {
                float x = bf2f(sM[(w*16+q*4+r)*168 + nt*16+col]) + aF3[nt][r];
                xv[nt][r] = x; s[r] += x; ss[r] += x*x;
            }
        #pragma unroll
        for (int r = 0; r < 4; r++)
            for (int off = 1; off <= 8; off <<= 1) {
                s[r]  += __shfl_xor(s[r], off);
                ss[r] += __shfl_xor(ss[r], off);
            }
        float mu[4], rs[4];
        #pragma unroll
        for (int r = 0; r < 4; r++) {
            mu[r] = s[r] * (1.f/128.f);
            float var = ss[r] * (1.f/128.f) - mu[r]*mu[r];
            rs[r] = rsqrtf(fmaxf(var, 0.f) + 1e-5f);
        }
        #pragma unroll
        for (int nt = 0; nt < 8; nt++)
            #pragma unroll
            for (int r = 0; r < 4; r++) {
                int m = w*16+q*4+r, n = nt*16+col, gn = n0+m;
                if (gn < N_NODES) {
                    float h2 = (xv[nt][r]-mu[r])*rs[r]*(1.f+aFl[nt][r]) + aFl[nt+8][r];
                    stg1<F32>(out, (size_t)gn*HID + n, h2);
                    stg1<F32>(out, (size_t)OUT_RES + (size_t)gn*HID + n,
                              bf2f(sR1[m*128 + n]) + aF3[nt][r]);
                }
            }
    }

    if (t < 64) {
        int gn = n0 + t;
        if (gn < N_NODES) {
            #pragma unroll
            for (int j = 0; j < 3; j++)
                stg1<F32>(out, (size_t)OUT_CRD + (size_t)gn*3 + j,
                          ldg1<F32>(coords, (size_t)gn*3 + j) + cacc[(size_t)gn*3 + j]);
        }
    }
}

__global__ __launch_bounds__(256, 1)
void node_kernel(const int* __restrict__ flag,
                 const void* h, const void* res, const void* coords, const void* y,
                 const float* __restrict__ den, const float* __restrict__ hagg,
                 const float* __restrict__ cacc,
                 const u16* __restrict__ WoB, const u16* __restrict__ Wn1B,
                 const u16* __restrict__ Wn2B, const u16* __restrict__ Wf1B,
                 const u16* __restrict__ Wf2B,
                 const u16* __restrict__ cbn1, const u16* __restrict__ cbn2,
                 const u16* __restrict__ cbf1, const u16* __restrict__ cbf2,
                 void* out)
{
    __shared__ __align__(16) u16 sB[256*72];
    __shared__ __align__(16) u16 sG[2*64*72];
    __shared__ __align__(16) u16 sM[64*168];
    __shared__ __align__(16) u16 sM2[64*168];
    __shared__ __align__(16) u16 sR1[64*128];
    __shared__ __align__(16) u16 sH[64*136];
    __shared__ __align__(16) u16 sY[64*72];
    if (*flag)
        node_body<true>(h, res, coords, y, den, hagg, cacc, WoB, Wn1B, Wn2B,
                        Wf1B, Wf2B, cbn1, cbn2, cbf1, cbf2, out,
                        sB, sG, sM, sM2, sR1, sH, sY);
    else
        node_body<false>(h, res, coords, y, den, hagg, cacc, WoB, Wn1B, Wn2B,
                         Wf1B, Wf2B, cbn1, cbn2, cbf1, cbf2, out,
                         sB, sG, sM, sM2, sR1, sH, sY);
}

// ---------------------------------------------------------------------------
extern "C" void kernel_launch(void* const* d_in, const int* in_sizes, int n_in,
                              void* d_out, int out_size, void* d_ws, size_t ws_size,
                              hipStream_t stream)
{
    const void* h      = d_in[0];
    const void* coords = d_in[1];
    const void* a      = d_in[2];
    const void* y      = d_in[3];
    const void* res    = d_in[4];
    const int* src     = (const int*)d_in[5];
    const int* dst     = (const int*)d_in[6];

    char* ws = (char*)d_ws;
    int*   flag = (int*)(ws + FLAG_OFF);
    float* den  = (float*)(ws + DEN_OFF);
    float* cacc = (float*)(ws + CACC_OFF);
    float* hagg = (float*)(ws + HAGG_OFF);

    const int wn[16]  = {43680, 25600, 20480, 1280, 160, 160, 160, 16384,
                         20480, 160, 20480, 128, 16384, 256, 16384, 256};
    const int widx[16] = {7, 9, 12, 13, 11, 8, 10, 14, 15, 16, 17, 18, 19, 20, 21, 22};
    u64 off = CW_BASE;
    CvtArgs args;
    u64 offs[16];
    for (int i = 0; i < 16; i++) {
        args.src[i] = d_in[widx[i]];
        args.dstoff[i] = off;
        args.n[i] = wn[i];
        offs[i] = off;
        off += (u64)wn[i] * 2;
    }
    u64 bw1 = (off + 255) & ~(u64)255;
    u64 bw2 = bw1 + (u64)5*160*72*2;
    u64 bw3 = bw2 + (u64)3*160*72*2;
    u64 bw4 = bw3 + (u64)3*144*72*2;
    u64 bw5 = bw4 + (u64)2*128*72*2;
    u64 bw6 = bw5 + (u64)2*160*72*2;
    u64 bw7 = bw6 + (u64)3*128*72*2;
    u64 bw8 = bw7 + (u64)256*72*2;

    const u16* cbe1 = (const u16*)(ws + offs[5]);
    const u16* cbe2 = (const u16*)(ws + offs[6]);
    const u16* cbn1 = (const u16*)(ws + offs[9]);
    const u16* cbn2 = (const u16*)(ws + offs[11]);
    const u16* cbf1 = (const u16*)(ws + offs[13]);
    const u16* cbf2 = (const u16*)(ws + offs[15]);
    const u16* We1Tb = (const u16*)(ws + bw1);
    const u16* We2Tb = (const u16*)(ws + bw2);
    const u16* W3Tb  = (const u16*)(ws + bw3);
    const u16* WoB   = (const u16*)(ws + bw4);
    const u16* Wn1B  = (const u16*)(ws + bw5);
    const u16* Wn2B  = (const u16*)(ws + bw6);
    const u16* Wf1B  = (const u16*)(ws + bw7);
    const u16* Wf2B  = (const u16*)(ws + bw8);

    hipMemsetAsync(d_ws, 0, MEMSET_BYTES, stream);

    detect_kernel<<<1, 256, 0, stream>>>(h, flag);
    cvt_kernel<<<dim3(8, 16), 256, 0, stream>>>(flag, ws, args);
    blockw_kernel<<<64, 256, 0, stream>>>(flag, ws, bw1, bw2, bw3, bw4,
                                          bw5, bw6, bw7, bw8,
                                          d_in[7], d_in[9], d_in[12], d_in[13], d_in[11],
                                          d_in[14], d_in[15], d_in[17], d_in[19], d_in[21]);

    edge_kernel<<<N_EDGES/64, 256, 0, stream>>>(flag, h, coords, a, src, dst,
                                                We1Tb, We2Tb, W3Tb, cbe1, cbe2,
                                                den, hagg, cacc);

    node_kernel<<<(N_NODES + 63)/64, 256, 0, stream>>>(
        flag, h, res, coords, y, den, hagg, cacc,
        WoB, Wn1B, Wn2B, Wf1B, Wf2B, cbn1, cbn2, cbf1, cbf2, d_out);
}